// Round 1
// baseline (1424.136 us; speedup 1.0000x reference)
//
#include <hip/hip_runtime.h>

#define B_   16
#define N_   1024
#define KNN  20
#define NP   (B_ * N_)   // 16384

typedef short bf16x8 __attribute__((ext_vector_type(8)));
typedef float f32x4  __attribute__((ext_vector_type(4)));

__device__ __forceinline__ unsigned short f2bf(float f) {
  unsigned u = __float_as_uint(f);
  u += 0x7fffu + ((u >> 16) & 1u);   // RNE
  return (unsigned short)(u >> 16);
}

// ---------------------------------------------------------------------------
// Pairwise squared distances within each cloud: D[b,i,j] = ||x_i - x_j||^2
// Exact fp32 (kNN selection must not be perturbed). 64x64 tile per block,
// 16x16 threads, 4x4 micro-tile, C tiled by 16.
// ---------------------------------------------------------------------------
__global__ __launch_bounds__(256) void pairdist_kernel(
    const float* __restrict__ X, int LD, int coff, int C, float* __restrict__ D) {
  __shared__ float Xi[64][17];
  __shared__ float Xj[64][17];
  int b  = blockIdx.z;
  int i0 = blockIdx.y * 64, j0 = blockIdx.x * 64;
  int t  = threadIdx.x;
  int tx = t & 15, ty = t >> 4;
  float acc[4][4] = {};
  for (int c0 = 0; c0 < C; c0 += 16) {
    int cc = min(16, C - c0);
    if (tx < cc) {
      for (int r = ty; r < 64; r += 16) {
        Xi[r][tx] = X[(size_t)(b * N_ + i0 + r) * LD + coff + c0 + tx];
        Xj[r][tx] = X[(size_t)(b * N_ + j0 + r) * LD + coff + c0 + tx];
      }
    }
    __syncthreads();
    for (int c = 0; c < cc; ++c) {
      float a[4], bb[4];
#pragma unroll
      for (int p = 0; p < 4; ++p) a[p]  = Xi[ty * 4 + p][c];
#pragma unroll
      for (int q = 0; q < 4; ++q) bb[q] = Xj[tx * 4 + q][c];
#pragma unroll
      for (int p = 0; p < 4; ++p)
#pragma unroll
        for (int q = 0; q < 4; ++q) {
          float d = a[p] - bb[q];
          acc[p][q] = fmaf(d, d, acc[p][q]);
        }
    }
    __syncthreads();
  }
#pragma unroll
  for (int p = 0; p < 4; ++p) {
    float4 st = make_float4(acc[p][0], acc[p][1], acc[p][2], acc[p][3]);
    *(float4*)&D[(size_t)(b * N_ + i0 + ty * 4 + p) * N_ + j0 + tx * 4] = st;
  }
}

// ---------------------------------------------------------------------------
// Top-K=20 smallest distances per point. One wave per point. Packed key
// (dist_bits << 10 | j): fp32 >= 0 so bit order == value order; ties -> lowest
// j, matching jax.lax.top_k. Outputs GLOBAL point indices (b*N + j).
// ---------------------------------------------------------------------------
__global__ __launch_bounds__(256) void topk_kernel(
    const float* __restrict__ D, int* __restrict__ idx) {
  int w = threadIdx.x >> 6, lane = threadIdx.x & 63;
  int p = blockIdx.x * 4 + w;
  const float* row = D + (size_t)p * N_;
  unsigned long long key[16];
#pragma unroll
  for (int s = 0; s < 16; ++s) {
    float vv = row[lane + 64 * s];
    key[s] = ((unsigned long long)__float_as_uint(vv) << 10) | (unsigned)(lane + 64 * s);
  }
  int base = p & ~(N_ - 1);
  for (int k = 0; k < KNN; ++k) {
    unsigned long long m = key[0];
#pragma unroll
    for (int s = 1; s < 16; ++s) m = key[s] < m ? key[s] : m;
#pragma unroll
    for (int off = 32; off >= 1; off >>= 1) {
      unsigned long long o = __shfl_xor(m, off);
      if (o < m) m = o;
    }
    int j = (int)(m & 1023u);
    if (lane == 0) idx[p * KNN + k] = base + j;
    if ((j & 63) == lane) key[j >> 6] = ~0ull;
  }
}

// ---------------------------------------------------------------------------
// Per-point transform: u = x@(Wa_top - Wa_bot) + ba ; v = x@Wa_bot   (fp32)
// Block: 4 waves x 4 points each, 64 output channels per blockIdx.y.
// ---------------------------------------------------------------------------
__global__ __launch_bounds__(256) void transform_kernel(
    const float* __restrict__ X, int LD, int coff, int Cin, int Cmid,
    const float* __restrict__ Wa, const float* __restrict__ ba,
    float* __restrict__ u, float* __restrict__ v) {
  int w = threadIdx.x >> 6, lane = threadIdx.x & 63;
  int m  = blockIdx.y * 64 + lane;
  int p0 = blockIdx.x * 16 + w * 4;
  float ua[4] = {0.f, 0.f, 0.f, 0.f}, va[4] = {0.f, 0.f, 0.f, 0.f};
  for (int c = 0; c < Cin; ++c) {
    float wt = Wa[(size_t)c * Cmid + m];
    float wb = Wa[(size_t)(Cin + c) * Cmid + m];
    float wd = wt - wb;
#pragma unroll
    for (int i = 0; i < 4; ++i) {
      float xv = X[(size_t)(p0 + i) * LD + coff + c];
      ua[i] = fmaf(xv, wd, ua[i]);
      va[i] = fmaf(xv, wb, va[i]);
    }
  }
  float bias = ba[m];
#pragma unroll
  for (int i = 0; i < 4; ++i) {
    u[(size_t)(p0 + i) * Cmid + m] = ua[i] + bias;
    v[(size_t)(p0 + i) * Cmid + m] = va[i];
  }
}

// ---------------------------------------------------------------------------
// Transpose + convert Wb (Cmid x Cout, fp32) -> WbT (Cout x Cmid, bf16)
// ---------------------------------------------------------------------------
__global__ void cvtw_kernel(const float* __restrict__ W, unsigned short* __restrict__ out,
                            int Cmid, int Cout) {
  int i = blockIdx.x * 256 + threadIdx.x;
  if (i >= Cmid * Cout) return;
  int co = i / Cmid, c = i - co * Cmid;
  out[i] = f2bf(W[(size_t)c * Cout + co]);
}

// ---------------------------------------------------------------------------
// Edge MLP second GEMM + max-aggregate, bf16 MFMA 16x16x32 (fp32 acc).
// Block: 320 threads (5 waves) = 80 edge-rows = 4 whole points.
// Wave w owns 16-row tile w; loops over CG-column groups of WbT staged in LDS.
// 20 % 16 == 4 -> point boundaries are quad-aligned in C frags, so aggregation
// is: per-lane max over 4 regs -> qmax[20][CG] in LDS -> max over 5 quads/pt.
// A rows padded +8 bf16 (rows land 4 banks apart for b128 fragment reads).
// ---------------------------------------------------------------------------
template<int Cmid, int Cout, int CG>
__global__ __launch_bounds__(320) void edge_mlp_kernel(
    const float* __restrict__ u, const float* __restrict__ v, const int* __restrict__ idx,
    const unsigned short* __restrict__ wbt, const float* __restrict__ bb,
    float* __restrict__ xcat, int coff) {
  constexpr int AP = Cmid + 8;
  constexpr int T  = CG / 16;
  __shared__ __align__(16) unsigned short A_lds[80 * AP];
  __shared__ __align__(16) unsigned short W_lds[CG * AP];
  __shared__ float qmax[20 * CG];
  int tid = threadIdx.x, w = tid >> 6, lane = tid & 63;

  // Build A: e = relu(u_p + v_j) in bf16, rows = (point,k) edges.
  for (int rr = 0; rr < 16; ++rr) {
    int r  = w * 16 + rr;
    int rg = blockIdx.x * 80 + r;
    int p  = rg / 20;
    int j  = idx[p * 20 + (rg - p * 20)];
    const float2* up = (const float2*)(u + (size_t)p * Cmid);
    const float2* vp = (const float2*)(v + (size_t)j * Cmid);
    for (int s = lane; s < Cmid / 2; s += 64) {
      float2 a = up[s], bv = vp[s];
      float x0 = fmaxf(a.x + bv.x, 0.f);
      float x1 = fmaxf(a.y + bv.y, 0.f);
      unsigned pk = (unsigned)f2bf(x0) | ((unsigned)f2bf(x1) << 16);
      *(unsigned*)&A_lds[r * AP + 2 * s] = pk;
    }
  }

  int arow = (w * 16 + (lane & 15)) * AP + ((lane >> 4) * 8);
  int brow = (lane & 15) * AP + ((lane >> 4) * 8);
  int quad = lane >> 4, col = lane & 15;

  for (int cg = 0; cg < Cout / CG; ++cg) {
    __syncthreads();
    for (int i = tid; i < CG * (Cmid / 8); i += 320) {
      int rr = i / (Cmid / 8), q = i - rr * (Cmid / 8);
      *(int4*)&W_lds[rr * AP + q * 8] =
          *(const int4*)&wbt[(size_t)(cg * CG + rr) * Cmid + q * 8];
    }
    __syncthreads();
    f32x4 acc[T];
#pragma unroll
    for (int t = 0; t < T; ++t) acc[t] = (f32x4){0.f, 0.f, 0.f, 0.f};
#pragma unroll
    for (int k0 = 0; k0 < Cmid; k0 += 32) {
      bf16x8 af = *(const bf16x8*)&A_lds[arow + k0];
#pragma unroll
      for (int t = 0; t < T; ++t) {
        bf16x8 bf = *(const bf16x8*)&W_lds[brow + t * 16 * AP + k0];
        acc[t] = __builtin_amdgcn_mfma_f32_16x16x32_bf16(af, bf, acc[t], 0, 0, 0);
      }
    }
#pragma unroll
    for (int t = 0; t < T; ++t) {
      float m0 = fmaxf(fmaxf(acc[t][0], acc[t][1]), fmaxf(acc[t][2], acc[t][3]));
      qmax[(w * 4 + quad) * CG + t * 16 + col] = m0;
    }
    __syncthreads();
    for (int i = tid; i < 4 * CG; i += 320) {
      int pl = i / CG, c = i - pl * CG;
      float mm = qmax[(pl * 5 + 0) * CG + c];
#pragma unroll
      for (int qq = 1; qq < 5; ++qq) mm = fmaxf(mm, qmax[(pl * 5 + qq) * CG + c]);
      int pg = blockIdx.x * 4 + pl;
      xcat[(size_t)pg * 512 + coff + cg * CG + c] = mm + bb[cg * CG + c];
    }
  }
}

// ---------------------------------------------------------------------------
// Head kernels (fp32 throughout)
// ---------------------------------------------------------------------------
__global__ __launch_bounds__(256) void pool_kernel(const float* __restrict__ xcat,
                                                   float* __restrict__ pooled) {
  int b = blockIdx.x, c = blockIdx.y * 256 + threadIdx.x;
  float m = -__builtin_inff();
  for (int n = 0; n < N_; ++n)
    m = fmaxf(m, xcat[((size_t)b * N_ + n) * 512 + c]);
  pooled[b * 512 + c] = m;
}

__global__ __launch_bounds__(256) void lin1_kernel(const float* __restrict__ pooled,
                                                   const float* __restrict__ W,
                                                   const float* __restrict__ bias,
                                                   float* __restrict__ h) {
  int flat = blockIdx.x * 256 + threadIdx.x;
  int b = flat >> 10, m = flat & 1023;
  float s = 0.f;
  for (int c = 0; c < 512; ++c) s = fmaf(pooled[b * 512 + c], W[(size_t)c * 1024 + m], s);
  h[flat] = s + bias[m];
}

__global__ __launch_bounds__(256) void bn_kernel(const float* __restrict__ h,
                                                 const float* __restrict__ gamma,
                                                 const float* __restrict__ beta,
                                                 float* __restrict__ h2) {
  int m = blockIdx.x * 256 + threadIdx.x;
  float s = 0.f;
  for (int b = 0; b < 16; ++b) s += h[b * 1024 + m];
  float mu = s * (1.f / 16.f);
  float vv = 0.f;
  for (int b = 0; b < 16; ++b) { float d = h[b * 1024 + m] - mu; vv = fmaf(d, d, vv); }
  vv *= (1.f / 16.f);
  float rstd = rsqrtf(vv + 1e-5f);
  float g = gamma[m] * rstd, be = beta[m];
  for (int b = 0; b < 16; ++b) {
    float val = (h[b * 1024 + m] - mu) * g + be;
    h2[b * 1024 + m] = fmaxf(val, 0.f);
  }
}

__global__ __launch_bounds__(64) void lin2_kernel(const float* __restrict__ h2,
                                                  const float* __restrict__ W,
                                                  const float* __restrict__ bias,
                                                  float* __restrict__ out) {
  int b = blockIdx.x, lane = threadIdx.x;
  float logit = 0.f;
  if (lane < 40) {
    logit = bias[lane];
    for (int c = 0; c < 1024; ++c)
      logit = fmaf(h2[b * 1024 + c], W[(size_t)c * 40 + lane], logit);
  }
  float mv = (lane < 40) ? logit : -__builtin_inff();
#pragma unroll
  for (int off = 32; off >= 1; off >>= 1) mv = fmaxf(mv, __shfl_xor(mv, off));
  float e = (lane < 40) ? expf(logit - mv) : 0.f;
#pragma unroll
  for (int off = 32; off >= 1; off >>= 1) e += __shfl_xor(e, off);
  float lse = mv + logf(e);
  if (lane < 40) out[b * 40 + lane] = logit - lse;
}

// ---------------------------------------------------------------------------
extern "C" void kernel_launch(void* const* d_in, const int* in_sizes, int n_in,
                              void* d_out, int out_size, void* d_ws, size_t ws_size,
                              hipStream_t stream) {
  const float* pos    = (const float*)d_in[0];
  const float* W1a = (const float*)d_in[2];  const float* b1a = (const float*)d_in[3];
  const float* W1b = (const float*)d_in[4];  const float* b1b = (const float*)d_in[5];
  const float* W2a = (const float*)d_in[6];  const float* b2a = (const float*)d_in[7];
  const float* W2b = (const float*)d_in[8];  const float* b2b = (const float*)d_in[9];
  const float* W3a = (const float*)d_in[10]; const float* b3a = (const float*)d_in[11];
  const float* W3b = (const float*)d_in[12]; const float* b3b = (const float*)d_in[13];
  const float* W4a = (const float*)d_in[14]; const float* b4a = (const float*)d_in[15];
  const float* W4b = (const float*)d_in[16]; const float* b4b = (const float*)d_in[17];
  const float* lin1_w = (const float*)d_in[18]; const float* lin1_b = (const float*)d_in[19];
  const float* gamma  = (const float*)d_in[20]; const float* beta   = (const float*)d_in[21];
  const float* lin2_w = (const float*)d_in[22]; const float* lin2_b = (const float*)d_in[23];
  float* out = (float*)d_out;

  // workspace layout (~98 MB): u/v alias the D region (D dead after topk)
  char* ws = (char*)d_ws;
  size_t off = 0;
  auto alloc = [&](size_t bytes) {
    void* p = ws + off; off += (bytes + 255) & ~(size_t)255; return p;
  };
  float* xcat = (float*)alloc((size_t)NP * 512 * 4);   // 32 MB
  float* D    = (float*)alloc((size_t)NP * N_ * 4);    // 64 MB (u/v alias inside)
  int*   idx  = (int*)alloc((size_t)NP * KNN * 4);
  unsigned short* wbt1 = (unsigned short*)alloc(64 * 64 * 2);
  unsigned short* wbt2 = (unsigned short*)alloc(64 * 64 * 2);
  unsigned short* wbt3 = (unsigned short*)alloc(128 * 128 * 2);
  unsigned short* wbt4 = (unsigned short*)alloc(256 * 256 * 2);
  float* h      = (float*)alloc(16 * 1024 * 4);
  float* h2     = (float*)alloc(16 * 1024 * 4);
  float* pooled = (float*)alloc(16 * 512 * 4);
  float* u = D;                        // alias: valid (stream-ordered after topk)
  float* v = D + (size_t)NP * 256;

  cvtw_kernel<<<16,  256, 0, stream>>>(W1b, wbt1, 64, 64);
  cvtw_kernel<<<16,  256, 0, stream>>>(W2b, wbt2, 64, 64);
  cvtw_kernel<<<64,  256, 0, stream>>>(W3b, wbt3, 128, 128);
  cvtw_kernel<<<256, 256, 0, stream>>>(W4b, wbt4, 256, 256);

  dim3 pd_grid(16, 16, 16);
  // layer 1: in pos (C=3) -> xcat[:,0:64]
  pairdist_kernel<<<pd_grid, 256, 0, stream>>>(pos, 3, 0, 3, D);
  topk_kernel<<<NP / 4, 256, 0, stream>>>(D, idx);
  transform_kernel<<<dim3(NP / 16, 1), 256, 0, stream>>>(pos, 3, 0, 3, 64, W1a, b1a, u, v);
  edge_mlp_kernel<64, 64, 64><<<4096, 320, 0, stream>>>(u, v, idx, wbt1, b1b, xcat, 0);
  // layer 2: in xcat[:,0:64] -> xcat[:,64:128]
  pairdist_kernel<<<pd_grid, 256, 0, stream>>>(xcat, 512, 0, 64, D);
  topk_kernel<<<NP / 4, 256, 0, stream>>>(D, idx);
  transform_kernel<<<dim3(NP / 16, 1), 256, 0, stream>>>(xcat, 512, 0, 64, 64, W2a, b2a, u, v);
  edge_mlp_kernel<64, 64, 64><<<4096, 320, 0, stream>>>(u, v, idx, wbt2, b2b, xcat, 64);
  // layer 3: in xcat[:,64:128] -> xcat[:,128:256]
  pairdist_kernel<<<pd_grid, 256, 0, stream>>>(xcat, 512, 64, 64, D);
  topk_kernel<<<NP / 4, 256, 0, stream>>>(D, idx);
  transform_kernel<<<dim3(NP / 16, 2), 256, 0, stream>>>(xcat, 512, 64, 64, 128, W3a, b3a, u, v);
  edge_mlp_kernel<128, 128, 64><<<4096, 320, 0, stream>>>(u, v, idx, wbt3, b3b, xcat, 128);
  // layer 4: in xcat[:,128:256] -> xcat[:,256:512]
  pairdist_kernel<<<pd_grid, 256, 0, stream>>>(xcat, 512, 128, 128, D);
  topk_kernel<<<NP / 4, 256, 0, stream>>>(D, idx);
  transform_kernel<<<dim3(NP / 16, 4), 256, 0, stream>>>(xcat, 512, 128, 128, 256, W4a, b4a, u, v);
  edge_mlp_kernel<256, 256, 32><<<4096, 320, 0, stream>>>(u, v, idx, wbt4, b4b, xcat, 256);
  // head
  pool_kernel<<<dim3(16, 2), 256, 0, stream>>>(xcat, pooled);
  lin1_kernel<<<64, 256, 0, stream>>>(pooled, lin1_w, lin1_b, h);
  bn_kernel<<<4, 256, 0, stream>>>(h, gamma, beta, h2);
  lin2_kernel<<<16, 64, 0, stream>>>(h2, lin2_w, lin2_b, out);
}

// Round 2
// 1193.140 us; speedup vs baseline: 1.1936x; 1.1936x over previous
//
#include <hip/hip_runtime.h>
#include <hip/hip_bf16.h>

#define B_   16
#define N_   1024
#define KNN  20
#define NP   (B_ * N_)   // 16384

typedef short bf16x8 __attribute__((ext_vector_type(8)));
typedef float f32x4  __attribute__((ext_vector_type(4)));

__device__ __forceinline__ unsigned short f2bf(float f) {
  unsigned u = __float_as_uint(f);
  u += 0x7fffu + ((u >> 16) & 1u);   // RNE
  return (unsigned short)(u >> 16);
}

// ---------------------------------------------------------------------------
// Pairwise squared distances within each cloud: D[b,i,j] = ||x_i - x_j||^2
// Exact fp32 (kNN selection must not be perturbed). 64x64 tile per block,
// 16x16 threads, 4x4 micro-tile, C tiled by 16.
// ---------------------------------------------------------------------------
__global__ __launch_bounds__(256) void pairdist_kernel(
    const float* __restrict__ X, int LD, int coff, int C, float* __restrict__ D) {
  __shared__ float Xi[64][17];
  __shared__ float Xj[64][17];
  int b  = blockIdx.z;
  int i0 = blockIdx.y * 64, j0 = blockIdx.x * 64;
  int t  = threadIdx.x;
  int tx = t & 15, ty = t >> 4;
  float acc[4][4] = {};
  for (int c0 = 0; c0 < C; c0 += 16) {
    int cc = min(16, C - c0);
    if (tx < cc) {
      for (int r = ty; r < 64; r += 16) {
        Xi[r][tx] = X[(size_t)(b * N_ + i0 + r) * LD + coff + c0 + tx];
        Xj[r][tx] = X[(size_t)(b * N_ + j0 + r) * LD + coff + c0 + tx];
      }
    }
    __syncthreads();
    for (int c = 0; c < cc; ++c) {
      float a[4], bb[4];
#pragma unroll
      for (int p = 0; p < 4; ++p) a[p]  = Xi[ty * 4 + p][c];
#pragma unroll
      for (int q = 0; q < 4; ++q) bb[q] = Xj[tx * 4 + q][c];
#pragma unroll
      for (int p = 0; p < 4; ++p)
#pragma unroll
        for (int q = 0; q < 4; ++q) {
          float d = a[p] - bb[q];
          acc[p][q] = fmaf(d, d, acc[p][q]);
        }
    }
    __syncthreads();
  }
#pragma unroll
  for (int p = 0; p < 4; ++p) {
    float4 st = make_float4(acc[p][0], acc[p][1], acc[p][2], acc[p][3]);
    *(float4*)&D[(size_t)(b * N_ + i0 + ty * 4 + p) * N_ + j0 + tx * 4] = st;
  }
}

// ---------------------------------------------------------------------------
// Top-K=20 smallest distances per point. One wave per point. Packed key
// (dist_bits << 10 | j): fp32 >= 0 so bit order == value order; ties -> lowest
// j, matching jax.lax.top_k. Outputs GLOBAL point indices (b*N + j).
// ---------------------------------------------------------------------------
__global__ __launch_bounds__(256) void topk_kernel(
    const float* __restrict__ D, int* __restrict__ idx) {
  int w = threadIdx.x >> 6, lane = threadIdx.x & 63;
  int p = blockIdx.x * 4 + w;
  const float* row = D + (size_t)p * N_;
  unsigned long long key[16];
#pragma unroll
  for (int s = 0; s < 16; ++s) {
    float vv = row[lane + 64 * s];
    key[s] = ((unsigned long long)__float_as_uint(vv) << 10) | (unsigned)(lane + 64 * s);
  }
  int base = p & ~(N_ - 1);
  for (int k = 0; k < KNN; ++k) {
    unsigned long long m = key[0];
#pragma unroll
    for (int s = 1; s < 16; ++s) m = key[s] < m ? key[s] : m;
#pragma unroll
    for (int off = 32; off >= 1; off >>= 1) {
      unsigned long long o = __shfl_xor(m, off);
      if (o < m) m = o;
    }
    int j = (int)(m & 1023u);
    if (lane == 0) idx[p * KNN + k] = base + j;
    if ((j & 63) == lane) key[j >> 6] = ~0ull;
  }
}

// ---------------------------------------------------------------------------
// Per-point transform: u = x@(Wa_top - Wa_bot) + ba ; v = x@Wa_bot   (fp32)
// ---------------------------------------------------------------------------
__global__ __launch_bounds__(256) void transform_kernel(
    const float* __restrict__ X, int LD, int coff, int Cin, int Cmid,
    const float* __restrict__ Wa, const float* __restrict__ ba,
    float* __restrict__ u, float* __restrict__ v) {
  int w = threadIdx.x >> 6, lane = threadIdx.x & 63;
  int m  = blockIdx.y * 64 + lane;
  int p0 = blockIdx.x * 16 + w * 4;
  float ua[4] = {0.f, 0.f, 0.f, 0.f}, va[4] = {0.f, 0.f, 0.f, 0.f};
  for (int c = 0; c < Cin; ++c) {
    float wt = Wa[(size_t)c * Cmid + m];
    float wb = Wa[(size_t)(Cin + c) * Cmid + m];
    float wd = wt - wb;
#pragma unroll
    for (int i = 0; i < 4; ++i) {
      float xv = X[(size_t)(p0 + i) * LD + coff + c];
      ua[i] = fmaf(xv, wd, ua[i]);
      va[i] = fmaf(xv, wb, va[i]);
    }
  }
  float bias = ba[m];
#pragma unroll
  for (int i = 0; i < 4; ++i) {
    u[(size_t)(p0 + i) * Cmid + m] = ua[i] + bias;
    v[(size_t)(p0 + i) * Cmid + m] = va[i];
  }
}

// ---------------------------------------------------------------------------
// Transpose + convert Wb (Cmid x Cout, fp32) -> WbT (Cout x Cmid, bf16)
// ---------------------------------------------------------------------------
__global__ void cvtw_kernel(const float* __restrict__ W, unsigned short* __restrict__ out,
                            int Cmid, int Cout) {
  int i = blockIdx.x * 256 + threadIdx.x;
  if (i >= Cmid * Cout) return;
  int co = i / Cmid, c = i - co * Cmid;
  out[i] = f2bf(W[(size_t)c * Cout + co]);
}

// ---------------------------------------------------------------------------
// Edge MLP second GEMM + max-aggregate, bf16 MFMA 16x16x32 (fp32 acc). v2:
//  - A-fragments built DIRECTLY IN REGISTERS from global u/v (no LDS A tile,
//    no A barriers, no A bank conflicts). MFMA A layout: lane -> row=lane&15,
//    k=quad*8+j, i.e. two float4 loads each from u[p] and v[j] per 32-k chunk.
//  - A-frags cached in VGPRs across all Cout groups (amortizes gather+cvt).
//  - LDS = one W column-group (CG=64) + qmax only => 39KB for L4 -> 4 blk/CU.
// Block: 320 threads (5 waves) = 80 edge-rows = 4 whole points.
// ---------------------------------------------------------------------------
template<int Cmid, int Cout, int CG>
__global__ __launch_bounds__(320) void edge_mlp_kernel(
    const float* __restrict__ u, const float* __restrict__ v, const int* __restrict__ idx,
    const unsigned short* __restrict__ wbt, const float* __restrict__ bb,
    float* __restrict__ xcat, int coff) {
  constexpr int AP = Cmid + 8;
  constexpr int T  = CG / 16;      // col tiles per group
  constexpr int KC = Cmid / 32;    // k chunks
  constexpr int G  = Cout / CG;    // col groups
  __shared__ __align__(16) unsigned short W_lds[CG * AP];
  __shared__ float qmax[20 * CG];
  int tid = threadIdx.x, w = tid >> 6, lane = tid & 63;
  int quad = lane >> 4, col = lane & 15;

  // This lane's edge row (row = col within wave-tile; same for all 4 quads).
  int rg = blockIdx.x * 80 + w * 16 + col;
  int p  = rg / 20;
  int j  = idx[rg];                 // idx is flat [p][k] == [rg]
  const float* up = u + (size_t)p * Cmid + quad * 8;
  const float* vp = v + (size_t)j * Cmid + quad * 8;

  // Build & cache A-fragments: relu(u+v) -> bf16, 8 elems/lane per 32-k chunk.
  bf16x8 afr[KC];
#pragma unroll
  for (int c = 0; c < KC; ++c) {
    float4 u0 = *(const float4*)(up + c * 32);
    float4 u1 = *(const float4*)(up + c * 32 + 4);
    float4 v0 = *(const float4*)(vp + c * 32);
    float4 v1 = *(const float4*)(vp + c * 32 + 4);
    union { bf16x8 vec; __hip_bfloat162 h[4]; } pk;
    pk.h[0] = __float22bfloat162_rn({fmaxf(u0.x + v0.x, 0.f), fmaxf(u0.y + v0.y, 0.f)});
    pk.h[1] = __float22bfloat162_rn({fmaxf(u0.z + v0.z, 0.f), fmaxf(u0.w + v0.w, 0.f)});
    pk.h[2] = __float22bfloat162_rn({fmaxf(u1.x + v1.x, 0.f), fmaxf(u1.y + v1.y, 0.f)});
    pk.h[3] = __float22bfloat162_rn({fmaxf(u1.z + v1.z, 0.f), fmaxf(u1.w + v1.w, 0.f)});
    afr[c] = pk.vec;
  }

  int brow = col * AP + quad * 8;

  for (int g = 0; g < G; ++g) {
    __syncthreads();   // W(g-1) reads + qmax(g-1) reduce done
    for (int i = tid; i < CG * (Cmid / 8); i += 320) {
      int rr = i / (Cmid / 8), q = i - rr * (Cmid / 8);
      *(int4*)&W_lds[rr * AP + q * 8] =
          *(const int4*)&wbt[(size_t)(g * CG + rr) * Cmid + q * 8];
    }
    __syncthreads();
    f32x4 acc[T];
#pragma unroll
    for (int t = 0; t < T; ++t) acc[t] = (f32x4){0.f, 0.f, 0.f, 0.f};
#pragma unroll
    for (int c = 0; c < KC; ++c) {
#pragma unroll
      for (int t = 0; t < T; ++t) {
        bf16x8 bf = *(const bf16x8*)&W_lds[brow + t * 16 * AP + c * 32];
        acc[t] = __builtin_amdgcn_mfma_f32_16x16x32_bf16(afr[c], bf, acc[t], 0, 0, 0);
      }
    }
#pragma unroll
    for (int t = 0; t < T; ++t) {
      float m0 = fmaxf(fmaxf(acc[t][0], acc[t][1]), fmaxf(acc[t][2], acc[t][3]));
      qmax[(w * 4 + quad) * CG + t * 16 + col] = m0;
    }
    __syncthreads();
    for (int i = tid; i < 4 * CG; i += 320) {
      int pl = i / CG, c2 = i - pl * CG;
      float mm = qmax[(pl * 5 + 0) * CG + c2];
#pragma unroll
      for (int qq = 1; qq < 5; ++qq) mm = fmaxf(mm, qmax[(pl * 5 + qq) * CG + c2]);
      int pg = blockIdx.x * 4 + pl;
      xcat[(size_t)pg * 512 + coff + g * CG + c2] = mm + bb[g * CG + c2];
    }
  }
}

// ---------------------------------------------------------------------------
// Head kernels (fp32 throughout)
// ---------------------------------------------------------------------------
__global__ __launch_bounds__(256) void pool_kernel(const float* __restrict__ xcat,
                                                   float* __restrict__ pooled) {
  int b = blockIdx.x, c = blockIdx.y * 256 + threadIdx.x;
  float m = -__builtin_inff();
  for (int n = 0; n < N_; ++n)
    m = fmaxf(m, xcat[((size_t)b * N_ + n) * 512 + c]);
  pooled[b * 512 + c] = m;
}

__global__ __launch_bounds__(256) void lin1_kernel(const float* __restrict__ pooled,
                                                   const float* __restrict__ W,
                                                   const float* __restrict__ bias,
                                                   float* __restrict__ h) {
  int flat = blockIdx.x * 256 + threadIdx.x;
  int b = flat >> 10, m = flat & 1023;
  float s = 0.f;
  for (int c = 0; c < 512; ++c) s = fmaf(pooled[b * 512 + c], W[(size_t)c * 1024 + m], s);
  h[flat] = s + bias[m];
}

__global__ __launch_bounds__(256) void bn_kernel(const float* __restrict__ h,
                                                 const float* __restrict__ gamma,
                                                 const float* __restrict__ beta,
                                                 float* __restrict__ h2) {
  int m = blockIdx.x * 256 + threadIdx.x;
  float s = 0.f;
  for (int b = 0; b < 16; ++b) s += h[b * 1024 + m];
  float mu = s * (1.f / 16.f);
  float vv = 0.f;
  for (int b = 0; b < 16; ++b) { float d = h[b * 1024 + m] - mu; vv = fmaf(d, d, vv); }
  vv *= (1.f / 16.f);
  float rstd = rsqrtf(vv + 1e-5f);
  float g = gamma[m] * rstd, be = beta[m];
  for (int b = 0; b < 16; ++b) {
    float val = (h[b * 1024 + m] - mu) * g + be;
    h2[b * 1024 + m] = fmaxf(val, 0.f);
  }
}

__global__ __launch_bounds__(64) void lin2_kernel(const float* __restrict__ h2,
                                                  const float* __restrict__ W,
                                                  const float* __restrict__ bias,
                                                  float* __restrict__ out) {
  int b = blockIdx.x, lane = threadIdx.x;
  float logit = 0.f;
  if (lane < 40) {
    logit = bias[lane];
    for (int c = 0; c < 1024; ++c)
      logit = fmaf(h2[b * 1024 + c], W[(size_t)c * 40 + lane], logit);
  }
  float mv = (lane < 40) ? logit : -__builtin_inff();
#pragma unroll
  for (int off = 32; off >= 1; off >>= 1) mv = fmaxf(mv, __shfl_xor(mv, off));
  float e = (lane < 40) ? expf(logit - mv) : 0.f;
#pragma unroll
  for (int off = 32; off >= 1; off >>= 1) e += __shfl_xor(e, off);
  float lse = mv + logf(e);
  if (lane < 40) out[b * 40 + lane] = logit - lse;
}

// ---------------------------------------------------------------------------
extern "C" void kernel_launch(void* const* d_in, const int* in_sizes, int n_in,
                              void* d_out, int out_size, void* d_ws, size_t ws_size,
                              hipStream_t stream) {
  const float* pos    = (const float*)d_in[0];
  const float* W1a = (const float*)d_in[2];  const float* b1a = (const float*)d_in[3];
  const float* W1b = (const float*)d_in[4];  const float* b1b = (const float*)d_in[5];
  const float* W2a = (const float*)d_in[6];  const float* b2a = (const float*)d_in[7];
  const float* W2b = (const float*)d_in[8];  const float* b2b = (const float*)d_in[9];
  const float* W3a = (const float*)d_in[10]; const float* b3a = (const float*)d_in[11];
  const float* W3b = (const float*)d_in[12]; const float* b3b = (const float*)d_in[13];
  const float* W4a = (const float*)d_in[14]; const float* b4a = (const float*)d_in[15];
  const float* W4b = (const float*)d_in[16]; const float* b4b = (const float*)d_in[17];
  const float* lin1_w = (const float*)d_in[18]; const float* lin1_b = (const float*)d_in[19];
  const float* gamma  = (const float*)d_in[20]; const float* beta   = (const float*)d_in[21];
  const float* lin2_w = (const float*)d_in[22]; const float* lin2_b = (const float*)d_in[23];
  float* out = (float*)d_out;

  // workspace layout (~98 MB): u/v alias the D region (D dead after topk)
  char* ws = (char*)d_ws;
  size_t off = 0;
  auto alloc = [&](size_t bytes) {
    void* p = ws + off; off += (bytes + 255) & ~(size_t)255; return p;
  };
  float* xcat = (float*)alloc((size_t)NP * 512 * 4);   // 32 MB
  float* D    = (float*)alloc((size_t)NP * N_ * 4);    // 64 MB (u/v alias inside)
  int*   idx  = (int*)alloc((size_t)NP * KNN * 4);
  unsigned short* wbt1 = (unsigned short*)alloc(64 * 64 * 2);
  unsigned short* wbt2 = (unsigned short*)alloc(64 * 64 * 2);
  unsigned short* wbt3 = (unsigned short*)alloc(128 * 128 * 2);
  unsigned short* wbt4 = (unsigned short*)alloc(256 * 256 * 2);
  float* h      = (float*)alloc(16 * 1024 * 4);
  float* h2     = (float*)alloc(16 * 1024 * 4);
  float* pooled = (float*)alloc(16 * 512 * 4);
  float* u = D;                        // alias: valid (stream-ordered after topk)
  float* v = D + (size_t)NP * 256;

  cvtw_kernel<<<16,  256, 0, stream>>>(W1b, wbt1, 64, 64);
  cvtw_kernel<<<16,  256, 0, stream>>>(W2b, wbt2, 64, 64);
  cvtw_kernel<<<64,  256, 0, stream>>>(W3b, wbt3, 128, 128);
  cvtw_kernel<<<256, 256, 0, stream>>>(W4b, wbt4, 256, 256);

  dim3 pd_grid(16, 16, 16);
  // layer 1: in pos (C=3) -> xcat[:,0:64]
  pairdist_kernel<<<pd_grid, 256, 0, stream>>>(pos, 3, 0, 3, D);
  topk_kernel<<<NP / 4, 256, 0, stream>>>(D, idx);
  transform_kernel<<<dim3(NP / 16, 1), 256, 0, stream>>>(pos, 3, 0, 3, 64, W1a, b1a, u, v);
  edge_mlp_kernel<64, 64, 64><<<4096, 320, 0, stream>>>(u, v, idx, wbt1, b1b, xcat, 0);
  // layer 2: in xcat[:,0:64] -> xcat[:,64:128]
  pairdist_kernel<<<pd_grid, 256, 0, stream>>>(xcat, 512, 0, 64, D);
  topk_kernel<<<NP / 4, 256, 0, stream>>>(D, idx);
  transform_kernel<<<dim3(NP / 16, 1), 256, 0, stream>>>(xcat, 512, 0, 64, 64, W2a, b2a, u, v);
  edge_mlp_kernel<64, 64, 64><<<4096, 320, 0, stream>>>(u, v, idx, wbt2, b2b, xcat, 64);
  // layer 3: in xcat[:,64:128] -> xcat[:,128:256]
  pairdist_kernel<<<pd_grid, 256, 0, stream>>>(xcat, 512, 64, 64, D);
  topk_kernel<<<NP / 4, 256, 0, stream>>>(D, idx);
  transform_kernel<<<dim3(NP / 16, 2), 256, 0, stream>>>(xcat, 512, 64, 64, 128, W3a, b3a, u, v);
  edge_mlp_kernel<128, 128, 64><<<4096, 320, 0, stream>>>(u, v, idx, wbt3, b3b, xcat, 128);
  // layer 4: in xcat[:,128:256] -> xcat[:,256:512]
  pairdist_kernel<<<pd_grid, 256, 0, stream>>>(xcat, 512, 128, 128, D);
  topk_kernel<<<NP / 4, 256, 0, stream>>>(D, idx);
  transform_kernel<<<dim3(NP / 16, 4), 256, 0, stream>>>(xcat, 512, 128, 128, 256, W4a, b4a, u, v);
  edge_mlp_kernel<256, 256, 64><<<4096, 320, 0, stream>>>(u, v, idx, wbt4, b4b, xcat, 256);
  // head
  pool_kernel<<<dim3(16, 2), 256, 0, stream>>>(xcat, pooled);
  lin1_kernel<<<64, 256, 0, stream>>>(pooled, lin1_w, lin1_b, h);
  bn_kernel<<<4, 256, 0, stream>>>(h, gamma, beta, h2);
  lin2_kernel<<<16, 64, 0, stream>>>(h2, lin2_w, lin2_b, out);
}

// Round 3
// 1100.568 us; speedup vs baseline: 1.2940x; 1.0841x over previous
//
#include <hip/hip_runtime.h>
#include <hip/hip_bf16.h>

#define B_   16
#define N_   1024
#define KNN  20
#define NP   (B_ * N_)   // 16384

typedef short bf16x8 __attribute__((ext_vector_type(8)));
typedef float f32x4  __attribute__((ext_vector_type(4)));
typedef float f32x16 __attribute__((ext_vector_type(16)));

__device__ __forceinline__ unsigned short f2bf(float f) {
  unsigned u = __float_as_uint(f);
  u += 0x7fffu + ((u >> 16) & 1u);   // RNE
  return (unsigned short)(u >> 16);
}

// ---------------------------------------------------------------------------
// Pairwise squared distances within each cloud: D[b,i,j] = ||x_i - x_j||^2
// Exact fp32 (kNN selection must not be perturbed). 64x64 tile per block,
// 16x16 threads, 4x4 micro-tile, C tiled by 16.
// ---------------------------------------------------------------------------
__global__ __launch_bounds__(256) void pairdist_kernel(
    const float* __restrict__ X, int LD, int coff, int C, float* __restrict__ D) {
  __shared__ float Xi[64][17];
  __shared__ float Xj[64][17];
  int b  = blockIdx.z;
  int i0 = blockIdx.y * 64, j0 = blockIdx.x * 64;
  int t  = threadIdx.x;
  int tx = t & 15, ty = t >> 4;
  float acc[4][4] = {};
  for (int c0 = 0; c0 < C; c0 += 16) {
    int cc = min(16, C - c0);
    if (tx < cc) {
      for (int r = ty; r < 64; r += 16) {
        Xi[r][tx] = X[(size_t)(b * N_ + i0 + r) * LD + coff + c0 + tx];
        Xj[r][tx] = X[(size_t)(b * N_ + j0 + r) * LD + coff + c0 + tx];
      }
    }
    __syncthreads();
    for (int c = 0; c < cc; ++c) {
      float a[4], bb[4];
#pragma unroll
      for (int p = 0; p < 4; ++p) a[p]  = Xi[ty * 4 + p][c];
#pragma unroll
      for (int q = 0; q < 4; ++q) bb[q] = Xj[tx * 4 + q][c];
#pragma unroll
      for (int p = 0; p < 4; ++p)
#pragma unroll
        for (int q = 0; q < 4; ++q) {
          float d = a[p] - bb[q];
          acc[p][q] = fmaf(d, d, acc[p][q]);
        }
    }
    __syncthreads();
  }
#pragma unroll
  for (int p = 0; p < 4; ++p) {
    float4 st = make_float4(acc[p][0], acc[p][1], acc[p][2], acc[p][3]);
    *(float4*)&D[(size_t)(b * N_ + i0 + ty * 4 + p) * N_ + j0 + tx * 4] = st;
  }
}

// ---------------------------------------------------------------------------
// Top-K=20 smallest distances per point. One wave per point. Packed key
// (dist_bits << 10 | j): fp32 >= 0 so bit order == value order; ties -> lowest
// j, matching jax.lax.top_k. Outputs GLOBAL point indices (b*N + j).
// ---------------------------------------------------------------------------
__global__ __launch_bounds__(256) void topk_kernel(
    const float* __restrict__ D, int* __restrict__ idx) {
  int w = threadIdx.x >> 6, lane = threadIdx.x & 63;
  int p = blockIdx.x * 4 + w;
  const float* row = D + (size_t)p * N_;
  unsigned long long key[16];
#pragma unroll
  for (int s = 0; s < 16; ++s) {
    float vv = row[lane + 64 * s];
    key[s] = ((unsigned long long)__float_as_uint(vv) << 10) | (unsigned)(lane + 64 * s);
  }
  int base = p & ~(N_ - 1);
  for (int k = 0; k < KNN; ++k) {
    unsigned long long m = key[0];
#pragma unroll
    for (int s = 1; s < 16; ++s) m = key[s] < m ? key[s] : m;
#pragma unroll
    for (int off = 32; off >= 1; off >>= 1) {
      unsigned long long o = __shfl_xor(m, off);
      if (o < m) m = o;
    }
    int j = (int)(m & 1023u);
    if (lane == 0) idx[p * KNN + k] = base + j;
    if ((j & 63) == lane) key[j >> 6] = ~0ull;
  }
}

// ---------------------------------------------------------------------------
// Per-point transform: u = x@(Wa_top - Wa_bot) + ba ; v = x@Wa_bot   (fp32)
// ---------------------------------------------------------------------------
__global__ __launch_bounds__(256) void transform_kernel(
    const float* __restrict__ X, int LD, int coff, int Cin, int Cmid,
    const float* __restrict__ Wa, const float* __restrict__ ba,
    float* __restrict__ u, float* __restrict__ v) {
  int w = threadIdx.x >> 6, lane = threadIdx.x & 63;
  int m  = blockIdx.y * 64 + lane;
  int p0 = blockIdx.x * 16 + w * 4;
  float ua[4] = {0.f, 0.f, 0.f, 0.f}, va[4] = {0.f, 0.f, 0.f, 0.f};
  for (int c = 0; c < Cin; ++c) {
    float wt = Wa[(size_t)c * Cmid + m];
    float wb = Wa[(size_t)(Cin + c) * Cmid + m];
    float wd = wt - wb;
#pragma unroll
    for (int i = 0; i < 4; ++i) {
      float xv = X[(size_t)(p0 + i) * LD + coff + c];
      ua[i] = fmaf(xv, wd, ua[i]);
      va[i] = fmaf(xv, wb, va[i]);
    }
  }
  float bias = ba[m];
#pragma unroll
  for (int i = 0; i < 4; ++i) {
    u[(size_t)(p0 + i) * Cmid + m] = ua[i] + bias;
    v[(size_t)(p0 + i) * Cmid + m] = va[i];
  }
}

// ---------------------------------------------------------------------------
// Transpose + convert Wb (Cmid x Cout, fp32) -> WbT (Cout x Cmid, bf16).
// LDS 32x32 tile: both global sides coalesced.
// ---------------------------------------------------------------------------
__global__ __launch_bounds__(256) void cvtw_kernel(
    const float* __restrict__ W, unsigned short* __restrict__ out, int Cmid, int Cout) {
  __shared__ unsigned short tile[32][33];
  int c0 = blockIdx.x * 32, co0 = blockIdx.y * 32;
  int tx = threadIdx.x & 31, ty = threadIdx.x >> 5;   // 32 x 8
  for (int r = ty; r < 32; r += 8)
    tile[r][tx] = f2bf(W[(size_t)(c0 + r) * Cout + co0 + tx]);
  __syncthreads();
  for (int r = ty; r < 32; r += 8)
    out[(size_t)(co0 + r) * Cmid + c0 + tx] = tile[tx][r];
}

// ---------------------------------------------------------------------------
// Edge MLP second GEMM + max-aggregate. v3: mfma_f32_32x32x16_bf16.
//  - One ds_read_b128 (1KB) now feeds 16K MACs (2x v2's bytes/MAC ratio).
//  - Block: 320 threads (5 waves) = 160 edges = 8 points (LCM(32,20)=160).
//  - A-frags (relu(u_p+v_j) bf16) built in regs from global; layout
//    row=lane&31, k=(lane>>5)*8+j. Cached across all Cout groups.
//  - C/D rows (reg&3)+8*(reg>>2)+4*(lane>>5): 4-row reg-quads align with
//    20-row point boundaries -> per-quad max -> qmax[40][CG] -> 5 groups/pt.
// ---------------------------------------------------------------------------
template<int Cmid, int Cout, int CG>
__global__ __launch_bounds__(320) void edge_mlp_kernel(
    const float* __restrict__ u, const float* __restrict__ v, const int* __restrict__ idx,
    const unsigned short* __restrict__ wbt, const float* __restrict__ bb,
    float* __restrict__ xcat, int coff) {
  constexpr int AP = Cmid + 8;
  constexpr int T  = CG / 32;      // 32-col tiles per group
  constexpr int KC = Cmid / 16;    // k chunks of 16
  constexpr int G  = Cout / CG;    // col groups
  __shared__ __align__(16) unsigned short W_lds[CG * AP];
  __shared__ float qmax[40 * CG];
  int tid = threadIdx.x, w = tid >> 6, lane = tid & 63;
  int col = lane & 31, half = lane >> 5;

  int rg = blockIdx.x * 160 + w * 32 + col;
  int p  = rg / 20;
  int j  = idx[rg];
  const float* up = u + (size_t)p * Cmid + half * 8;
  const float* vp = v + (size_t)j * Cmid + half * 8;

  bf16x8 afr[KC];
#pragma unroll
  for (int c = 0; c < KC; ++c) {
    float4 u0 = *(const float4*)(up + c * 16);
    float4 u1 = *(const float4*)(up + c * 16 + 4);
    float4 v0 = *(const float4*)(vp + c * 16);
    float4 v1 = *(const float4*)(vp + c * 16 + 4);
    union { bf16x8 vec; __hip_bfloat162 h[4]; } pk;
    pk.h[0] = __float22bfloat162_rn({fmaxf(u0.x + v0.x, 0.f), fmaxf(u0.y + v0.y, 0.f)});
    pk.h[1] = __float22bfloat162_rn({fmaxf(u0.z + v0.z, 0.f), fmaxf(u0.w + v0.w, 0.f)});
    pk.h[2] = __float22bfloat162_rn({fmaxf(u1.x + v1.x, 0.f), fmaxf(u1.y + v1.y, 0.f)});
    pk.h[3] = __float22bfloat162_rn({fmaxf(u1.z + v1.z, 0.f), fmaxf(u1.w + v1.w, 0.f)});
    afr[c] = pk.vec;
  }

  int brow = col * AP + half * 8;

  for (int g = 0; g < G; ++g) {
    __syncthreads();   // W(g-1) MFMA reads + qmax(g-1) tail reads done
    for (int i = tid; i < CG * (Cmid / 8); i += 320) {
      int rr = i / (Cmid / 8), q = i - rr * (Cmid / 8);
      *(int4*)&W_lds[rr * AP + q * 8] =
          *(const int4*)&wbt[(size_t)(g * CG + rr) * Cmid + q * 8];
    }
    __syncthreads();
    f32x16 acc[T] = {};
#pragma unroll
    for (int c = 0; c < KC; ++c) {
#pragma unroll
      for (int t = 0; t < T; ++t) {
        bf16x8 bf = *(const bf16x8*)&W_lds[brow + t * 32 * AP + c * 16];
        acc[t] = __builtin_amdgcn_mfma_f32_32x32x16_bf16(afr[c], bf, acc[t], 0, 0, 0);
      }
    }
#pragma unroll
    for (int t = 0; t < T; ++t) {
#pragma unroll
      for (int Q = 0; Q < 4; ++Q) {
        float m0 = fmaxf(fmaxf(acc[t][4 * Q], acc[t][4 * Q + 1]),
                         fmaxf(acc[t][4 * Q + 2], acc[t][4 * Q + 3]));
        qmax[(w * 8 + 2 * Q + half) * CG + t * 32 + col] = m0;
      }
    }
    __syncthreads();
    for (int i = tid; i < 8 * CG; i += 320) {
      int pl = i / CG, c2 = i - pl * CG;
      float mm = qmax[(pl * 5 + 0) * CG + c2];
#pragma unroll
      for (int qq = 1; qq < 5; ++qq) mm = fmaxf(mm, qmax[(pl * 5 + qq) * CG + c2]);
      int pg = blockIdx.x * 8 + pl;
      xcat[(size_t)pg * 512 + coff + g * CG + c2] = mm + bb[g * CG + c2];
    }
  }
}

// ---------------------------------------------------------------------------
// Global max pool, two-stage coalesced.
// pool1: grid (16 clouds, 8 chunks) x 256 thr; each block streams 128 rows
//        x 512 cols (256 KB contiguous) -> part[b][g][512].
// pool2: 16 blocks reduce 8 partials.
// ---------------------------------------------------------------------------
__global__ __launch_bounds__(256) void pool1_kernel(const float* __restrict__ xcat,
                                                    float* __restrict__ part) {
  int b = blockIdx.x, g = blockIdx.y, t = threadIdx.x;
  const float* base = xcat + ((size_t)b * N_ + g * 128) * 512 + t * 2;
  float mx = -__builtin_inff(), my = -__builtin_inff();
#pragma unroll 4
  for (int r = 0; r < 128; ++r) {
    float2 vv = *(const float2*)(base + (size_t)r * 512);
    mx = fmaxf(mx, vv.x);
    my = fmaxf(my, vv.y);
  }
  *(float2*)&part[((size_t)b * 8 + g) * 512 + t * 2] = make_float2(mx, my);
}

__global__ __launch_bounds__(256) void pool2_kernel(const float* __restrict__ part,
                                                    float* __restrict__ pooled) {
  int b = blockIdx.x, t = threadIdx.x;
  float2 m = *(const float2*)&part[(size_t)b * 8 * 512 + t * 2];
#pragma unroll
  for (int g = 1; g < 8; ++g) {
    float2 vv = *(const float2*)&part[((size_t)b * 8 + g) * 512 + t * 2];
    m.x = fmaxf(m.x, vv.x);
    m.y = fmaxf(m.y, vv.y);
  }
  *(float2*)&pooled[b * 512 + t * 2] = m;
}

__global__ __launch_bounds__(256) void lin1_kernel(const float* __restrict__ pooled,
                                                   const float* __restrict__ W,
                                                   const float* __restrict__ bias,
                                                   float* __restrict__ h) {
  int flat = blockIdx.x * 256 + threadIdx.x;
  int b = flat >> 10, m = flat & 1023;
  float s = 0.f;
  for (int c = 0; c < 512; ++c) s = fmaf(pooled[b * 512 + c], W[(size_t)c * 1024 + m], s);
  h[flat] = s + bias[m];
}

__global__ __launch_bounds__(256) void bn_kernel(const float* __restrict__ h,
                                                 const float* __restrict__ gamma,
                                                 const float* __restrict__ beta,
                                                 float* __restrict__ h2) {
  int m = blockIdx.x * 256 + threadIdx.x;
  float s = 0.f;
  for (int b = 0; b < 16; ++b) s += h[b * 1024 + m];
  float mu = s * (1.f / 16.f);
  float vv = 0.f;
  for (int b = 0; b < 16; ++b) { float d = h[b * 1024 + m] - mu; vv = fmaf(d, d, vv); }
  vv *= (1.f / 16.f);
  float rstd = rsqrtf(vv + 1e-5f);
  float g = gamma[m] * rstd, be = beta[m];
  for (int b = 0; b < 16; ++b) {
    float val = (h[b * 1024 + m] - mu) * g + be;
    h2[b * 1024 + m] = fmaxf(val, 0.f);
  }
}

__global__ __launch_bounds__(64) void lin2_kernel(const float* __restrict__ h2,
                                                  const float* __restrict__ W,
                                                  const float* __restrict__ bias,
                                                  float* __restrict__ out) {
  int b = blockIdx.x, lane = threadIdx.x;
  float logit = 0.f;
  if (lane < 40) {
    logit = bias[lane];
    for (int c = 0; c < 1024; ++c)
      logit = fmaf(h2[b * 1024 + c], W[(size_t)c * 40 + lane], logit);
  }
  float mv = (lane < 40) ? logit : -__builtin_inff();
#pragma unroll
  for (int off = 32; off >= 1; off >>= 1) mv = fmaxf(mv, __shfl_xor(mv, off));
  float e = (lane < 40) ? expf(logit - mv) : 0.f;
#pragma unroll
  for (int off = 32; off >= 1; off >>= 1) e += __shfl_xor(e, off);
  float lse = mv + logf(e);
  if (lane < 40) out[b * 40 + lane] = logit - lse;
}

// ---------------------------------------------------------------------------
extern "C" void kernel_launch(void* const* d_in, const int* in_sizes, int n_in,
                              void* d_out, int out_size, void* d_ws, size_t ws_size,
                              hipStream_t stream) {
  const float* pos    = (const float*)d_in[0];
  const float* W1a = (const float*)d_in[2];  const float* b1a = (const float*)d_in[3];
  const float* W1b = (const float*)d_in[4];  const float* b1b = (const float*)d_in[5];
  const float* W2a = (const float*)d_in[6];  const float* b2a = (const float*)d_in[7];
  const float* W2b = (const float*)d_in[8];  const float* b2b = (const float*)d_in[9];
  const float* W3a = (const float*)d_in[10]; const float* b3a = (const float*)d_in[11];
  const float* W3b = (const float*)d_in[12]; const float* b3b = (const float*)d_in[13];
  const float* W4a = (const float*)d_in[14]; const float* b4a = (const float*)d_in[15];
  const float* W4b = (const float*)d_in[16]; const float* b4b = (const float*)d_in[17];
  const float* lin1_w = (const float*)d_in[18]; const float* lin1_b = (const float*)d_in[19];
  const float* gamma  = (const float*)d_in[20]; const float* beta   = (const float*)d_in[21];
  const float* lin2_w = (const float*)d_in[22]; const float* lin2_b = (const float*)d_in[23];
  float* out = (float*)d_out;

  char* ws = (char*)d_ws;
  size_t off = 0;
  auto alloc = [&](size_t bytes) {
    void* p = ws + off; off += (bytes + 255) & ~(size_t)255; return p;
  };
  float* xcat = (float*)alloc((size_t)NP * 512 * 4);   // 32 MB
  float* D    = (float*)alloc((size_t)NP * N_ * 4);    // 64 MB (u/v alias inside)
  int*   idx  = (int*)alloc((size_t)NP * KNN * 4);
  unsigned short* wbt1 = (unsigned short*)alloc(64 * 64 * 2);
  unsigned short* wbt2 = (unsigned short*)alloc(64 * 64 * 2);
  unsigned short* wbt3 = (unsigned short*)alloc(128 * 128 * 2);
  unsigned short* wbt4 = (unsigned short*)alloc(256 * 256 * 2);
  float* h      = (float*)alloc(16 * 1024 * 4);
  float* h2     = (float*)alloc(16 * 1024 * 4);
  float* pooled = (float*)alloc(16 * 512 * 4);
  float* part   = (float*)alloc(16 * 8 * 512 * 4);
  float* u = D;                        // alias: valid (stream-ordered after topk)
  float* v = D + (size_t)NP * 256;

  cvtw_kernel<<<dim3(2, 2),   256, 0, stream>>>(W1b, wbt1, 64, 64);
  cvtw_kernel<<<dim3(2, 2),   256, 0, stream>>>(W2b, wbt2, 64, 64);
  cvtw_kernel<<<dim3(4, 4),   256, 0, stream>>>(W3b, wbt3, 128, 128);
  cvtw_kernel<<<dim3(8, 8),   256, 0, stream>>>(W4b, wbt4, 256, 256);

  dim3 pd_grid(16, 16, 16);
  // layer 1: in pos (C=3) -> xcat[:,0:64]
  pairdist_kernel<<<pd_grid, 256, 0, stream>>>(pos, 3, 0, 3, D);
  topk_kernel<<<NP / 4, 256, 0, stream>>>(D, idx);
  transform_kernel<<<dim3(NP / 16, 1), 256, 0, stream>>>(pos, 3, 0, 3, 64, W1a, b1a, u, v);
  edge_mlp_kernel<64, 64, 64><<<2048, 320, 0, stream>>>(u, v, idx, wbt1, b1b, xcat, 0);
  // layer 2: in xcat[:,0:64] -> xcat[:,64:128]
  pairdist_kernel<<<pd_grid, 256, 0, stream>>>(xcat, 512, 0, 64, D);
  topk_kernel<<<NP / 4, 256, 0, stream>>>(D, idx);
  transform_kernel<<<dim3(NP / 16, 1), 256, 0, stream>>>(xcat, 512, 0, 64, 64, W2a, b2a, u, v);
  edge_mlp_kernel<64, 64, 64><<<2048, 320, 0, stream>>>(u, v, idx, wbt2, b2b, xcat, 64);
  // layer 3: in xcat[:,64:128] -> xcat[:,128:256]
  pairdist_kernel<<<pd_grid, 256, 0, stream>>>(xcat, 512, 64, 64, D);
  topk_kernel<<<NP / 4, 256, 0, stream>>>(D, idx);
  transform_kernel<<<dim3(NP / 16, 2), 256, 0, stream>>>(xcat, 512, 64, 64, 128, W3a, b3a, u, v);
  edge_mlp_kernel<128, 128, 64><<<2048, 320, 0, stream>>>(u, v, idx, wbt3, b3b, xcat, 128);
  // layer 4: in xcat[:,128:256] -> xcat[:,256:512]
  pairdist_kernel<<<pd_grid, 256, 0, stream>>>(xcat, 512, 128, 128, D);
  topk_kernel<<<NP / 4, 256, 0, stream>>>(D, idx);
  transform_kernel<<<dim3(NP / 16, 4), 256, 0, stream>>>(xcat, 512, 128, 128, 256, W4a, b4a, u, v);
  edge_mlp_kernel<256, 256, 32><<<2048, 320, 0, stream>>>(u, v, idx, wbt4, b4b, xcat, 256);
  // head
  pool1_kernel<<<dim3(16, 8), 256, 0, stream>>>(xcat, part);
  pool2_kernel<<<16, 256, 0, stream>>>(part, pooled);
  lin1_kernel<<<64, 256, 0, stream>>>(pooled, lin1_w, lin1_b, h);
  bn_kernel<<<4, 256, 0, stream>>>(h, gamma, beta, h2);
  lin2_kernel<<<16, 64, 0, stream>>>(h2, lin2_w, lin2_b, out);
}

// Round 4
// 983.868 us; speedup vs baseline: 1.4475x; 1.1186x over previous
//
#include <hip/hip_runtime.h>
#include <hip/hip_bf16.h>

#define B_   16
#define N_   1024
#define KNN  20
#define NP   (B_ * N_)   // 16384

typedef short bf16x8 __attribute__((ext_vector_type(8)));
typedef float f32x4  __attribute__((ext_vector_type(4)));
typedef float f32x16 __attribute__((ext_vector_type(16)));

__device__ __forceinline__ unsigned short f2bf(float f) {
  unsigned u = __float_as_uint(f);
  u += 0x7fffu + ((u >> 16) & 1u);   // RNE
  return (unsigned short)(u >> 16);
}

// ---------------------------------------------------------------------------
// Pairwise squared distances within each cloud: D[b,i,j] = ||x_i - x_j||^2
// Exact fp32 (kNN selection must not be perturbed). 64x64 tile per block,
// 16x16 threads, 4x4 micro-tile, C tiled by 16.
// ---------------------------------------------------------------------------
__global__ __launch_bounds__(256) void pairdist_kernel(
    const float* __restrict__ X, int LD, int coff, int C, float* __restrict__ D) {
  __shared__ float Xi[64][17];
  __shared__ float Xj[64][17];
  int b  = blockIdx.z;
  int i0 = blockIdx.y * 64, j0 = blockIdx.x * 64;
  int t  = threadIdx.x;
  int tx = t & 15, ty = t >> 4;
  float acc[4][4] = {};
  for (int c0 = 0; c0 < C; c0 += 16) {
    int cc = min(16, C - c0);
    if (tx < cc) {
      for (int r = ty; r < 64; r += 16) {
        Xi[r][tx] = X[(size_t)(b * N_ + i0 + r) * LD + coff + c0 + tx];
        Xj[r][tx] = X[(size_t)(b * N_ + j0 + r) * LD + coff + c0 + tx];
      }
    }
    __syncthreads();
    for (int c = 0; c < cc; ++c) {
      float a[4], bb[4];
#pragma unroll
      for (int p = 0; p < 4; ++p) a[p]  = Xi[ty * 4 + p][c];
#pragma unroll
      for (int q = 0; q < 4; ++q) bb[q] = Xj[tx * 4 + q][c];
#pragma unroll
      for (int p = 0; p < 4; ++p)
#pragma unroll
        for (int q = 0; q < 4; ++q) {
          float d = a[p] - bb[q];
          acc[p][q] = fmaf(d, d, acc[p][q]);
        }
    }
    __syncthreads();
  }
#pragma unroll
  for (int p = 0; p < 4; ++p) {
    float4 st = make_float4(acc[p][0], acc[p][1], acc[p][2], acc[p][3]);
    *(float4*)&D[(size_t)(b * N_ + i0 + ty * 4 + p) * N_ + j0 + tx * 4] = st;
  }
}

// ---------------------------------------------------------------------------
// Top-K=20 smallest distances per point. One wave per point. Packed key
// (dist_bits << 10 | j): ties -> lowest j, matching jax.lax.top_k.
// ---------------------------------------------------------------------------
__global__ __launch_bounds__(256) void topk_kernel(
    const float* __restrict__ D, int* __restrict__ idx) {
  int w = threadIdx.x >> 6, lane = threadIdx.x & 63;
  int p = blockIdx.x * 4 + w;
  const float* row = D + (size_t)p * N_;
  unsigned long long key[16];
#pragma unroll
  for (int s = 0; s < 16; ++s) {
    float vv = row[lane + 64 * s];
    key[s] = ((unsigned long long)__float_as_uint(vv) << 10) | (unsigned)(lane + 64 * s);
  }
  int base = p & ~(N_ - 1);
  for (int k = 0; k < KNN; ++k) {
    unsigned long long m = key[0];
#pragma unroll
    for (int s = 1; s < 16; ++s) m = key[s] < m ? key[s] : m;
#pragma unroll
    for (int off = 32; off >= 1; off >>= 1) {
      unsigned long long o = __shfl_xor(m, off);
      if (o < m) m = o;
    }
    int j = (int)(m & 1023u);
    if (lane == 0) idx[p * KNN + k] = base + j;
    if ((j & 63) == lane) key[j >> 6] = ~0ull;
  }
}

// ---------------------------------------------------------------------------
// Per-point transform: u = x@(Wa_top - Wa_bot) + ba ; v = x@Wa_bot
// fp32 accumulate, OUTPUT bf16 (halves edge-gather traffic + registers).
// ---------------------------------------------------------------------------
__global__ __launch_bounds__(256) void transform_kernel(
    const float* __restrict__ X, int LD, int coff, int Cin, int Cmid,
    const float* __restrict__ Wa, const float* __restrict__ ba,
    unsigned short* __restrict__ u, unsigned short* __restrict__ v) {
  int w = threadIdx.x >> 6, lane = threadIdx.x & 63;
  int m  = blockIdx.y * 64 + lane;
  int p0 = blockIdx.x * 16 + w * 4;
  float ua[4] = {0.f, 0.f, 0.f, 0.f}, va[4] = {0.f, 0.f, 0.f, 0.f};
  for (int c = 0; c < Cin; ++c) {
    float wt = Wa[(size_t)c * Cmid + m];
    float wb = Wa[(size_t)(Cin + c) * Cmid + m];
    float wd = wt - wb;
#pragma unroll
    for (int i = 0; i < 4; ++i) {
      float xv = X[(size_t)(p0 + i) * LD + coff + c];
      ua[i] = fmaf(xv, wd, ua[i]);
      va[i] = fmaf(xv, wb, va[i]);
    }
  }
  float bias = ba[m];
#pragma unroll
  for (int i = 0; i < 4; ++i) {
    u[(size_t)(p0 + i) * Cmid + m] = f2bf(ua[i] + bias);
    v[(size_t)(p0 + i) * Cmid + m] = f2bf(va[i]);
  }
}

// ---------------------------------------------------------------------------
// Transpose + convert Wb (Cmid x Cout, fp32) -> WbT (Cout x Cmid, bf16).
// ---------------------------------------------------------------------------
__global__ __launch_bounds__(256) void cvtw_kernel(
    const float* __restrict__ W, unsigned short* __restrict__ out, int Cmid, int Cout) {
  __shared__ unsigned short tile[32][33];
  int c0 = blockIdx.x * 32, co0 = blockIdx.y * 32;
  int tx = threadIdx.x & 31, ty = threadIdx.x >> 5;   // 32 x 8
  for (int r = ty; r < 32; r += 8)
    tile[r][tx] = f2bf(W[(size_t)(c0 + r) * Cout + co0 + tx]);
  __syncthreads();
  for (int r = ty; r < 32; r += 8)
    out[(size_t)(co0 + r) * Cmid + c0 + tx] = tile[tx][r];
}

// ---------------------------------------------------------------------------
// Edge MLP second GEMM + max-aggregate. v4: mfma_f32_32x32x16_bf16, bf16 u/v.
//  - Block: 320 threads (5 waves) = 160 edges = 8 points (LCM(32,20)=160).
//  - A-frags (relu(u_p+v_j), bf16 in / fp32 add / bf16 out) built in regs
//    from 16B bf16x8 global loads; cached across all Cout groups.
//  - __launch_bounds__(320,4): force <=128 unified regs -> 4 waves/SIMD.
//  - C/D rows (reg&3)+8*(reg>>2)+4*(lane>>5): per-reg-quad max -> qmax LDS.
// ---------------------------------------------------------------------------
template<int Cmid, int Cout, int CG>
__global__ __launch_bounds__(320, 4) void edge_mlp_kernel(
    const unsigned short* __restrict__ u, const unsigned short* __restrict__ v,
    const int* __restrict__ idx,
    const unsigned short* __restrict__ wbt, const float* __restrict__ bb,
    float* __restrict__ xcat, int coff) {
  constexpr int AP = Cmid + 8;
  constexpr int T  = CG / 32;      // 32-col tiles per group
  constexpr int KC = Cmid / 16;    // k chunks of 16
  constexpr int G  = Cout / CG;    // col groups
  __shared__ __align__(16) unsigned short W_lds[CG * AP];
  __shared__ float qmax[40 * CG];
  int tid = threadIdx.x, w = tid >> 6, lane = tid & 63;
  int col = lane & 31, half = lane >> 5;

  int rg = blockIdx.x * 160 + w * 32 + col;
  int p  = rg / 20;
  int j  = idx[rg];
  const unsigned short* up = u + (size_t)p * Cmid + half * 8;
  const unsigned short* vp = v + (size_t)j * Cmid + half * 8;

  bf16x8 afr[KC];
#pragma unroll
  for (int c = 0; c < KC; ++c) {
    union { int4 i; __hip_bfloat162 h[4]; bf16x8 vec; } U, V, R;
    U.i = *(const int4*)(up + c * 16);
    V.i = *(const int4*)(vp + c * 16);
#pragma unroll
    for (int q = 0; q < 4; ++q) {
      float2 a = __bfloat1622float2(U.h[q]);
      float2 b = __bfloat1622float2(V.h[q]);
      R.h[q] = __float22bfloat162_rn({fmaxf(a.x + b.x, 0.f), fmaxf(a.y + b.y, 0.f)});
    }
    afr[c] = R.vec;
  }

  int brow = col * AP + half * 8;

  for (int g = 0; g < G; ++g) {
    __syncthreads();   // W(g-1) MFMA reads + qmax(g-1) tail reads done
    for (int i = tid; i < CG * (Cmid / 8); i += 320) {
      int rr = i / (Cmid / 8), q = i - rr * (Cmid / 8);
      *(int4*)&W_lds[rr * AP + q * 8] =
          *(const int4*)&wbt[(size_t)(g * CG + rr) * Cmid + q * 8];
    }
    __syncthreads();
    f32x16 acc[T] = {};
#pragma unroll
    for (int c = 0; c < KC; ++c) {
#pragma unroll
      for (int t = 0; t < T; ++t) {
        bf16x8 bf = *(const bf16x8*)&W_lds[brow + t * 32 * AP + c * 16];
        acc[t] = __builtin_amdgcn_mfma_f32_32x32x16_bf16(afr[c], bf, acc[t], 0, 0, 0);
      }
    }
#pragma unroll
    for (int t = 0; t < T; ++t) {
#pragma unroll
      for (int Q = 0; Q < 4; ++Q) {
        float m0 = fmaxf(fmaxf(acc[t][4 * Q], acc[t][4 * Q + 1]),
                         fmaxf(acc[t][4 * Q + 2], acc[t][4 * Q + 3]));
        qmax[(w * 8 + 2 * Q + half) * CG + t * 32 + col] = m0;
      }
    }
    __syncthreads();
    for (int i = tid; i < 8 * CG; i += 320) {
      int pl = i / CG, c2 = i - pl * CG;
      float mm = qmax[(pl * 5 + 0) * CG + c2];
#pragma unroll
      for (int qq = 1; qq < 5; ++qq) mm = fmaxf(mm, qmax[(pl * 5 + qq) * CG + c2]);
      int pg = blockIdx.x * 8 + pl;
      xcat[(size_t)pg * 512 + coff + g * CG + c2] = mm + bb[g * CG + c2];
    }
  }
}

// ---------------------------------------------------------------------------
// Global max pool, two-stage coalesced.
// ---------------------------------------------------------------------------
__global__ __launch_bounds__(256) void pool1_kernel(const float* __restrict__ xcat,
                                                    float* __restrict__ part) {
  int b = blockIdx.x, g = blockIdx.y, t = threadIdx.x;
  const float* base = xcat + ((size_t)b * N_ + g * 128) * 512 + t * 2;
  float mx = -__builtin_inff(), my = -__builtin_inff();
#pragma unroll 4
  for (int r = 0; r < 128; ++r) {
    float2 vv = *(const float2*)(base + (size_t)r * 512);
    mx = fmaxf(mx, vv.x);
    my = fmaxf(my, vv.y);
  }
  *(float2*)&part[((size_t)b * 8 + g) * 512 + t * 2] = make_float2(mx, my);
}

__global__ __launch_bounds__(256) void pool2_kernel(const float* __restrict__ part,
                                                    float* __restrict__ pooled) {
  int b = blockIdx.x, t = threadIdx.x;
  float2 m = *(const float2*)&part[(size_t)b * 8 * 512 + t * 2];
#pragma unroll
  for (int g = 1; g < 8; ++g) {
    float2 vv = *(const float2*)&part[((size_t)b * 8 + g) * 512 + t * 2];
    m.x = fmaxf(m.x, vv.x);
    m.y = fmaxf(m.y, vv.y);
  }
  *(float2*)&pooled[b * 512 + t * 2] = m;
}

__global__ __launch_bounds__(256) void lin1_kernel(const float* __restrict__ pooled,
                                                   const float* __restrict__ W,
                                                   const float* __restrict__ bias,
                                                   float* __restrict__ h) {
  int flat = blockIdx.x * 256 + threadIdx.x;
  int b = flat >> 10, m = flat & 1023;
  float s = 0.f;
  for (int c = 0; c < 512; ++c) s = fmaf(pooled[b * 512 + c], W[(size_t)c * 1024 + m], s);
  h[flat] = s + bias[m];
}

__global__ __launch_bounds__(256) void bn_kernel(const float* __restrict__ h,
                                                 const float* __restrict__ gamma,
                                                 const float* __restrict__ beta,
                                                 float* __restrict__ h2) {
  int m = blockIdx.x * 256 + threadIdx.x;
  float s = 0.f;
  for (int b = 0; b < 16; ++b) s += h[b * 1024 + m];
  float mu = s * (1.f / 16.f);
  float vv = 0.f;
  for (int b = 0; b < 16; ++b) { float d = h[b * 1024 + m] - mu; vv = fmaf(d, d, vv); }
  vv *= (1.f / 16.f);
  float rstd = rsqrtf(vv + 1e-5f);
  float g = gamma[m] * rstd, be = beta[m];
  for (int b = 0; b < 16; ++b) {
    float val = (h[b * 1024 + m] - mu) * g + be;
    h2[b * 1024 + m] = fmaxf(val, 0.f);
  }
}

__global__ __launch_bounds__(64) void lin2_kernel(const float* __restrict__ h2,
                                                  const float* __restrict__ W,
                                                  const float* __restrict__ bias,
                                                  float* __restrict__ out) {
  int b = blockIdx.x, lane = threadIdx.x;
  float logit = 0.f;
  if (lane < 40) {
    logit = bias[lane];
    for (int c = 0; c < 1024; ++c)
      logit = fmaf(h2[b * 1024 + c], W[(size_t)c * 40 + lane], logit);
  }
  float mv = (lane < 40) ? logit : -__builtin_inff();
#pragma unroll
  for (int off = 32; off >= 1; off >>= 1) mv = fmaxf(mv, __shfl_xor(mv, off));
  float e = (lane < 40) ? expf(logit - mv) : 0.f;
#pragma unroll
  for (int off = 32; off >= 1; off >>= 1) e += __shfl_xor(e, off);
  float lse = mv + logf(e);
  if (lane < 40) out[b * 40 + lane] = logit - lse;
}

// ---------------------------------------------------------------------------
extern "C" void kernel_launch(void* const* d_in, const int* in_sizes, int n_in,
                              void* d_out, int out_size, void* d_ws, size_t ws_size,
                              hipStream_t stream) {
  const float* pos    = (const float*)d_in[0];
  const float* W1a = (const float*)d_in[2];  const float* b1a = (const float*)d_in[3];
  const float* W1b = (const float*)d_in[4];  const float* b1b = (const float*)d_in[5];
  const float* W2a = (const float*)d_in[6];  const float* b2a = (const float*)d_in[7];
  const float* W2b = (const float*)d_in[8];  const float* b2b = (const float*)d_in[9];
  const float* W3a = (const float*)d_in[10]; const float* b3a = (const float*)d_in[11];
  const float* W3b = (const float*)d_in[12]; const float* b3b = (const float*)d_in[13];
  const float* W4a = (const float*)d_in[14]; const float* b4a = (const float*)d_in[15];
  const float* W4b = (const float*)d_in[16]; const float* b4b = (const float*)d_in[17];
  const float* lin1_w = (const float*)d_in[18]; const float* lin1_b = (const float*)d_in[19];
  const float* gamma  = (const float*)d_in[20]; const float* beta   = (const float*)d_in[21];
  const float* lin2_w = (const float*)d_in[22]; const float* lin2_b = (const float*)d_in[23];
  float* out = (float*)d_out;

  char* ws = (char*)d_ws;
  size_t off = 0;
  auto alloc = [&](size_t bytes) {
    void* p = ws + off; off += (bytes + 255) & ~(size_t)255; return p;
  };
  float* xcat = (float*)alloc((size_t)NP * 512 * 4);   // 32 MB
  float* D    = (float*)alloc((size_t)NP * N_ * 4);    // 64 MB (u/v alias inside)
  int*   idx  = (int*)alloc((size_t)NP * KNN * 4);
  unsigned short* wbt1 = (unsigned short*)alloc(64 * 64 * 2);
  unsigned short* wbt2 = (unsigned short*)alloc(64 * 64 * 2);
  unsigned short* wbt3 = (unsigned short*)alloc(128 * 128 * 2);
  unsigned short* wbt4 = (unsigned short*)alloc(256 * 256 * 2);
  float* h      = (float*)alloc(16 * 1024 * 4);
  float* h2     = (float*)alloc(16 * 1024 * 4);
  float* pooled = (float*)alloc(16 * 512 * 4);
  float* part   = (float*)alloc(16 * 8 * 512 * 4);
  unsigned short* u = (unsigned short*)D;              // 8 MB (bf16, aliases D)
  unsigned short* v = (unsigned short*)D + (size_t)NP * 256;

  cvtw_kernel<<<dim3(2, 2),   256, 0, stream>>>(W1b, wbt1, 64, 64);
  cvtw_kernel<<<dim3(2, 2),   256, 0, stream>>>(W2b, wbt2, 64, 64);
  cvtw_kernel<<<dim3(4, 4),   256, 0, stream>>>(W3b, wbt3, 128, 128);
  cvtw_kernel<<<dim3(8, 8),   256, 0, stream>>>(W4b, wbt4, 256, 256);

  dim3 pd_grid(16, 16, 16);
  // layer 1: in pos (C=3) -> xcat[:,0:64]
  pairdist_kernel<<<pd_grid, 256, 0, stream>>>(pos, 3, 0, 3, D);
  topk_kernel<<<NP / 4, 256, 0, stream>>>(D, idx);
  transform_kernel<<<dim3(NP / 16, 1), 256, 0, stream>>>(pos, 3, 0, 3, 64, W1a, b1a, u, v);
  edge_mlp_kernel<64, 64, 64><<<2048, 320, 0, stream>>>(u, v, idx, wbt1, b1b, xcat, 0);
  // layer 2: in xcat[:,0:64] -> xcat[:,64:128]
  pairdist_kernel<<<pd_grid, 256, 0, stream>>>(xcat, 512, 0, 64, D);
  topk_kernel<<<NP / 4, 256, 0, stream>>>(D, idx);
  transform_kernel<<<dim3(NP / 16, 1), 256, 0, stream>>>(xcat, 512, 0, 64, 64, W2a, b2a, u, v);
  edge_mlp_kernel<64, 64, 64><<<2048, 320, 0, stream>>>(u, v, idx, wbt2, b2b, xcat, 64);
  // layer 3: in xcat[:,64:128] -> xcat[:,128:256]
  pairdist_kernel<<<pd_grid, 256, 0, stream>>>(xcat, 512, 64, 64, D);
  topk_kernel<<<NP / 4, 256, 0, stream>>>(D, idx);
  transform_kernel<<<dim3(NP / 16, 2), 256, 0, stream>>>(xcat, 512, 64, 64, 128, W3a, b3a, u, v);
  edge_mlp_kernel<128, 128, 64><<<2048, 320, 0, stream>>>(u, v, idx, wbt3, b3b, xcat, 128);
  // layer 4: in xcat[:,128:256] -> xcat[:,256:512]
  pairdist_kernel<<<pd_grid, 256, 0, stream>>>(xcat, 512, 128, 128, D);
  topk_kernel<<<NP / 4, 256, 0, stream>>>(D, idx);
  transform_kernel<<<dim3(NP / 16, 4), 256, 0, stream>>>(xcat, 512, 128, 128, 256, W4a, b4a, u, v);
  edge_mlp_kernel<256, 256, 32><<<2048, 320, 0, stream>>>(u, v, idx, wbt4, b4b, xcat, 256);
  // head
  pool1_kernel<<<dim3(16, 8), 256, 0, stream>>>(xcat, part);
  pool2_kernel<<<16, 256, 0, stream>>>(part, pooled);
  lin1_kernel<<<64, 256, 0, stream>>>(pooled, lin1_w, lin1_b, h);
  bn_kernel<<<4, 256, 0, stream>>>(h, gamma, beta, h2);
  lin2_kernel<<<16, 64, 0, stream>>>(h2, lin2_w, lin2_b, out);
}

// Round 5
// 893.546 us; speedup vs baseline: 1.5938x; 1.1011x over previous
//
#include <hip/hip_runtime.h>
#include <hip/hip_bf16.h>

#define B_   16
#define N_   1024
#define KNN  20
#define NP   (B_ * N_)   // 16384

typedef short bf16x8 __attribute__((ext_vector_type(8)));
typedef float f32x4  __attribute__((ext_vector_type(4)));
typedef float f32x16 __attribute__((ext_vector_type(16)));

__device__ __forceinline__ unsigned short f2bf(float f) {
  unsigned u = __float_as_uint(f);
  u += 0x7fffu + ((u >> 16) & 1u);   // RNE
  return (unsigned short)(u >> 16);
}

// ---------------------------------------------------------------------------
// Row squared norms: sq[p] = sum_c X[p][c]^2  (fp32)
// ---------------------------------------------------------------------------
__global__ __launch_bounds__(256) void sqnorm_kernel(
    const float* __restrict__ X, int LD, int coff, int C, float* __restrict__ sq) {
  int p = blockIdx.x * 256 + threadIdx.x;
  const float* row = X + (size_t)p * LD + coff;
  float s = 0.f;
  if ((C & 3) == 0) {
    for (int c = 0; c < C; c += 4) {
      float4 vv = *(const float4*)(row + c);
      s = fmaf(vv.x, vv.x, s); s = fmaf(vv.y, vv.y, s);
      s = fmaf(vv.z, vv.z, s); s = fmaf(vv.w, vv.w, s);
    }
  } else {
    for (int c = 0; c < C; ++c) { float vv = row[c]; s = fmaf(vv, vv, s); }
  }
  sq[p] = s;
}

// ---------------------------------------------------------------------------
// Pairwise squared distances, Gram form (matches reference):
//   D[b,i,j] = (sq_i - 2*dot(x_i,x_j)) + sq_j
// fp32, fma-only inner loop. LDS tiles stored TRANSPOSED [c][row] with
// stride 68 (68%32==4 -> 2-way max on write, conflict-free b128 reads).
// 64x64 tile per block, 16x16 threads, 4x4 micro-tile.
// ---------------------------------------------------------------------------
__global__ __launch_bounds__(256) void pairdist_kernel(
    const float* __restrict__ X, int LD, int coff, int C,
    const float* __restrict__ sq, float* __restrict__ D) {
  __shared__ float Xi[16][68];
  __shared__ float Xj[16][68];
  int b  = blockIdx.z;
  int i0 = blockIdx.y * 64, j0 = blockIdx.x * 64;
  int t  = threadIdx.x;
  int tx = t & 15, ty = t >> 4;
  float acc[4][4] = {};
  for (int c0 = 0; c0 < C; c0 += 16) {
    int cc = min(16, C - c0);
    if (tx < cc) {
      for (int r = ty; r < 64; r += 16) {
        Xi[tx][r] = X[(size_t)(b * N_ + i0 + r) * LD + coff + c0 + tx];
        Xj[tx][r] = X[(size_t)(b * N_ + j0 + r) * LD + coff + c0 + tx];
      }
    }
    __syncthreads();
    for (int c = 0; c < cc; ++c) {
      float4 a4 = *(const float4*)&Xi[c][ty * 4];
      float4 b4 = *(const float4*)&Xj[c][tx * 4];
      float a[4] = {a4.x, a4.y, a4.z, a4.w};
      float bb[4] = {b4.x, b4.y, b4.z, b4.w};
#pragma unroll
      for (int p = 0; p < 4; ++p)
#pragma unroll
        for (int q = 0; q < 4; ++q)
          acc[p][q] = fmaf(a[p], bb[q], acc[p][q]);
    }
    __syncthreads();
  }
  float sqi[4], sqj[4];
#pragma unroll
  for (int p = 0; p < 4; ++p) sqi[p] = sq[b * N_ + i0 + ty * 4 + p];
#pragma unroll
  for (int q = 0; q < 4; ++q) sqj[q] = sq[b * N_ + j0 + tx * 4 + q];
#pragma unroll
  for (int p = 0; p < 4; ++p) {
    float4 st;
    st.x = (sqi[p] - 2.f * acc[p][0]) + sqj[0];
    st.y = (sqi[p] - 2.f * acc[p][1]) + sqj[1];
    st.z = (sqi[p] - 2.f * acc[p][2]) + sqj[2];
    st.w = (sqi[p] - 2.f * acc[p][3]) + sqj[3];
    *(float4*)&D[(size_t)(b * N_ + i0 + ty * 4 + p) * N_ + j0 + tx * 4] = st;
  }
}

// ---------------------------------------------------------------------------
// Top-K=20 smallest distances per point. One wave per point. Packed key
// (dist_bits << 10 | j): ties -> lowest j, matching jax.lax.top_k.
// ---------------------------------------------------------------------------
__global__ __launch_bounds__(256) void topk_kernel(
    const float* __restrict__ D, int* __restrict__ idx) {
  int w = threadIdx.x >> 6, lane = threadIdx.x & 63;
  int p = blockIdx.x * 4 + w;
  const float* row = D + (size_t)p * N_;
  unsigned long long key[16];
#pragma unroll
  for (int s = 0; s < 16; ++s) {
    float vv = row[lane + 64 * s];
    key[s] = ((unsigned long long)__float_as_uint(vv) << 10) | (unsigned)(lane + 64 * s);
  }
  int base = p & ~(N_ - 1);
  for (int k = 0; k < KNN; ++k) {
    unsigned long long m = key[0];
#pragma unroll
    for (int s = 1; s < 16; ++s) m = key[s] < m ? key[s] : m;
#pragma unroll
    for (int off = 32; off >= 1; off >>= 1) {
      unsigned long long o = __shfl_xor(m, off);
      if (o < m) m = o;
    }
    int j = (int)(m & 1023u);
    if (lane == 0) idx[p * KNN + k] = base + j;
    if ((j & 63) == lane) key[j >> 6] = ~0ull;
  }
}

// ---------------------------------------------------------------------------
// Per-point transform: u = x@(Wa_top - Wa_bot) + ba ; v = x@Wa_bot
// fp32 accumulate, bf16 out. v2: X rows staged in LDS (coalesced float4),
// inner loop reads LDS broadcast (free) + 2 coalesced Wa streams.
// ---------------------------------------------------------------------------
__global__ __launch_bounds__(256) void transform_kernel(
    const float* __restrict__ X, int LD, int coff, int Cin, int Cmid,
    const float* __restrict__ Wa, const float* __restrict__ ba,
    unsigned short* __restrict__ u, unsigned short* __restrict__ v) {
  __shared__ float xs[16 * 128];
  int w = threadIdx.x >> 6, lane = threadIdx.x & 63;
  int m  = blockIdx.y * 64 + lane;
  int p0 = blockIdx.x * 16;
  if ((Cin & 3) == 0) {
    for (int i = threadIdx.x; i < 16 * (Cin / 4); i += 256) {
      int pt = i / (Cin / 4), q = i - pt * (Cin / 4);
      *(float4*)&xs[pt * Cin + q * 4] =
          *(const float4*)&X[(size_t)(p0 + pt) * LD + coff + q * 4];
    }
  } else {
    for (int i = threadIdx.x; i < 16 * Cin; i += 256) {
      int pt = i / Cin, c = i - pt * Cin;
      xs[pt * Cin + c] = X[(size_t)(p0 + pt) * LD + coff + c];
    }
  }
  __syncthreads();
  const float* xw = xs + (w * 4) * Cin;
  float ua[4] = {0.f, 0.f, 0.f, 0.f}, va[4] = {0.f, 0.f, 0.f, 0.f};
  for (int c = 0; c < Cin; ++c) {
    float wt = Wa[(size_t)c * Cmid + m];
    float wb = Wa[(size_t)(Cin + c) * Cmid + m];
    float wd = wt - wb;
#pragma unroll
    for (int i = 0; i < 4; ++i) {
      float xv = xw[i * Cin + c];
      ua[i] = fmaf(xv, wd, ua[i]);
      va[i] = fmaf(xv, wb, va[i]);
    }
  }
  float bias = ba[m];
#pragma unroll
  for (int i = 0; i < 4; ++i) {
    u[(size_t)(p0 + w * 4 + i) * Cmid + m] = f2bf(ua[i] + bias);
    v[(size_t)(p0 + w * 4 + i) * Cmid + m] = f2bf(va[i]);
  }
}

// ---------------------------------------------------------------------------
// Transpose + convert Wb (Cmid x Cout, fp32) -> WbT (Cout x Cmid, bf16).
// ---------------------------------------------------------------------------
__global__ __launch_bounds__(256) void cvtw_kernel(
    const float* __restrict__ W, unsigned short* __restrict__ out, int Cmid, int Cout) {
  __shared__ unsigned short tile[32][33];
  int c0 = blockIdx.x * 32, co0 = blockIdx.y * 32;
  int tx = threadIdx.x & 31, ty = threadIdx.x >> 5;   // 32 x 8
  for (int r = ty; r < 32; r += 8)
    tile[r][tx] = f2bf(W[(size_t)(c0 + r) * Cout + co0 + tx]);
  __syncthreads();
  for (int r = ty; r < 32; r += 8)
    out[(size_t)(co0 + r) * Cmid + c0 + tx] = tile[tx][r];
}

// ---------------------------------------------------------------------------
// Edge MLP second GEMM + max-aggregate. mfma_f32_32x32x16_bf16, bf16 u/v.
// Block: 320 threads (5 waves) = 160 edges = 8 points (LCM(32,20)=160).
// A-frags built in regs from 16B bf16x8 global loads; cached across groups.
// ---------------------------------------------------------------------------
template<int Cmid, int Cout, int CG>
__global__ __launch_bounds__(320, 4) void edge_mlp_kernel(
    const unsigned short* __restrict__ u, const unsigned short* __restrict__ v,
    const int* __restrict__ idx,
    const unsigned short* __restrict__ wbt, const float* __restrict__ bb,
    float* __restrict__ xcat, int coff) {
  constexpr int AP = Cmid + 8;
  constexpr int T  = CG / 32;      // 32-col tiles per group
  constexpr int KC = Cmid / 16;    // k chunks of 16
  constexpr int G  = Cout / CG;    // col groups
  __shared__ __align__(16) unsigned short W_lds[CG * AP];
  __shared__ float qmax[40 * CG];
  int tid = threadIdx.x, w = tid >> 6, lane = tid & 63;
  int col = lane & 31, half = lane >> 5;

  int rg = blockIdx.x * 160 + w * 32 + col;
  int p  = rg / 20;
  int j  = idx[rg];
  const unsigned short* up = u + (size_t)p * Cmid + half * 8;
  const unsigned short* vp = v + (size_t)j * Cmid + half * 8;

  bf16x8 afr[KC];
#pragma unroll
  for (int c = 0; c < KC; ++c) {
    union { int4 i; __hip_bfloat162 h[4]; bf16x8 vec; } U, V, R;
    U.i = *(const int4*)(up + c * 16);
    V.i = *(const int4*)(vp + c * 16);
#pragma unroll
    for (int q = 0; q < 4; ++q) {
      float2 a = __bfloat1622float2(U.h[q]);
      float2 b = __bfloat1622float2(V.h[q]);
      R.h[q] = __float22bfloat162_rn({fmaxf(a.x + b.x, 0.f), fmaxf(a.y + b.y, 0.f)});
    }
    afr[c] = R.vec;
  }

  int brow = col * AP + half * 8;

  for (int g = 0; g < G; ++g) {
    __syncthreads();   // W(g-1) MFMA reads + qmax(g-1) tail reads done
    for (int i = tid; i < CG * (Cmid / 8); i += 320) {
      int rr = i / (Cmid / 8), q = i - rr * (Cmid / 8);
      *(int4*)&W_lds[rr * AP + q * 8] =
          *(const int4*)&wbt[(size_t)(g * CG + rr) * Cmid + q * 8];
    }
    __syncthreads();
    f32x16 acc[T] = {};
#pragma unroll
    for (int c = 0; c < KC; ++c) {
#pragma unroll
      for (int t = 0; t < T; ++t) {
        bf16x8 bf = *(const bf16x8*)&W_lds[brow + t * 32 * AP + c * 16];
        acc[t] = __builtin_amdgcn_mfma_f32_32x32x16_bf16(afr[c], bf, acc[t], 0, 0, 0);
      }
    }
#pragma unroll
    for (int t = 0; t < T; ++t) {
#pragma unroll
      for (int Q = 0; Q < 4; ++Q) {
        float m0 = fmaxf(fmaxf(acc[t][4 * Q], acc[t][4 * Q + 1]),
                         fmaxf(acc[t][4 * Q + 2], acc[t][4 * Q + 3]));
        qmax[(w * 8 + 2 * Q + half) * CG + t * 32 + col] = m0;
      }
    }
    __syncthreads();
    for (int i = tid; i < 8 * CG; i += 320) {
      int pl = i / CG, c2 = i - pl * CG;
      float mm = qmax[(pl * 5 + 0) * CG + c2];
#pragma unroll
      for (int qq = 1; qq < 5; ++qq) mm = fmaxf(mm, qmax[(pl * 5 + qq) * CG + c2]);
      int pg = blockIdx.x * 8 + pl;
      xcat[(size_t)pg * 512 + coff + g * CG + c2] = mm + bb[g * CG + c2];
    }
  }
}

// ---------------------------------------------------------------------------
// Global max pool, two-stage coalesced.
// ---------------------------------------------------------------------------
__global__ __launch_bounds__(256) void pool1_kernel(const float* __restrict__ xcat,
                                                    float* __restrict__ part) {
  int b = blockIdx.x, g = blockIdx.y, t = threadIdx.x;
  const float* base = xcat + ((size_t)b * N_ + g * 128) * 512 + t * 2;
  float mx = -__builtin_inff(), my = -__builtin_inff();
#pragma unroll 4
  for (int r = 0; r < 128; ++r) {
    float2 vv = *(const float2*)(base + (size_t)r * 512);
    mx = fmaxf(mx, vv.x);
    my = fmaxf(my, vv.y);
  }
  *(float2*)&part[((size_t)b * 8 + g) * 512 + t * 2] = make_float2(mx, my);
}

__global__ __launch_bounds__(256) void pool2_kernel(const float* __restrict__ part,
                                                    float* __restrict__ pooled) {
  int b = blockIdx.x, t = threadIdx.x;
  float2 m = *(const float2*)&part[(size_t)b * 8 * 512 + t * 2];
#pragma unroll
  for (int g = 1; g < 8; ++g) {
    float2 vv = *(const float2*)&part[((size_t)b * 8 + g) * 512 + t * 2];
    m.x = fmaxf(m.x, vv.x);
    m.y = fmaxf(m.y, vv.y);
  }
  *(float2*)&pooled[b * 512 + t * 2] = m;
}

__global__ __launch_bounds__(256) void lin1_kernel(const float* __restrict__ pooled,
                                                   const float* __restrict__ W,
                                                   const float* __restrict__ bias,
                                                   float* __restrict__ h) {
  int flat = blockIdx.x * 256 + threadIdx.x;
  int b = flat >> 10, m = flat & 1023;
  float s = 0.f;
  for (int c = 0; c < 512; ++c) s = fmaf(pooled[b * 512 + c], W[(size_t)c * 1024 + m], s);
  h[flat] = s + bias[m];
}

__global__ __launch_bounds__(256) void bn_kernel(const float* __restrict__ h,
                                                 const float* __restrict__ gamma,
                                                 const float* __restrict__ beta,
                                                 float* __restrict__ h2) {
  int m = blockIdx.x * 256 + threadIdx.x;
  float s = 0.f;
  for (int b = 0; b < 16; ++b) s += h[b * 1024 + m];
  float mu = s * (1.f / 16.f);
  float vv = 0.f;
  for (int b = 0; b < 16; ++b) { float d = h[b * 1024 + m] - mu; vv = fmaf(d, d, vv); }
  vv *= (1.f / 16.f);
  float rstd = rsqrtf(vv + 1e-5f);
  float g = gamma[m] * rstd, be = beta[m];
  for (int b = 0; b < 16; ++b) {
    float val = (h[b * 1024 + m] - mu) * g + be;
    h2[b * 1024 + m] = fmaxf(val, 0.f);
  }
}

__global__ __launch_bounds__(64) void lin2_kernel(const float* __restrict__ h2,
                                                  const float* __restrict__ W,
                                                  const float* __restrict__ bias,
                                                  float* __restrict__ out) {
  int b = blockIdx.x, lane = threadIdx.x;
  float logit = 0.f;
  if (lane < 40) {
    logit = bias[lane];
    for (int c = 0; c < 1024; ++c)
      logit = fmaf(h2[b * 1024 + c], W[(size_t)c * 40 + lane], logit);
  }
  float mv = (lane < 40) ? logit : -__builtin_inff();
#pragma unroll
  for (int off = 32; off >= 1; off >>= 1) mv = fmaxf(mv, __shfl_xor(mv, off));
  float e = (lane < 40) ? expf(logit - mv) : 0.f;
#pragma unroll
  for (int off = 32; off >= 1; off >>= 1) e += __shfl_xor(e, off);
  float lse = mv + logf(e);
  if (lane < 40) out[b * 40 + lane] = logit - lse;
}

// ---------------------------------------------------------------------------
extern "C" void kernel_launch(void* const* d_in, const int* in_sizes, int n_in,
                              void* d_out, int out_size, void* d_ws, size_t ws_size,
                              hipStream_t stream) {
  const float* pos    = (const float*)d_in[0];
  const float* W1a = (const float*)d_in[2];  const float* b1a = (const float*)d_in[3];
  const float* W1b = (const float*)d_in[4];  const float* b1b = (const float*)d_in[5];
  const float* W2a = (const float*)d_in[6];  const float* b2a = (const float*)d_in[7];
  const float* W2b = (const float*)d_in[8];  const float* b2b = (const float*)d_in[9];
  const float* W3a = (const float*)d_in[10]; const float* b3a = (const float*)d_in[11];
  const float* W3b = (const float*)d_in[12]; const float* b3b = (const float*)d_in[13];
  const float* W4a = (const float*)d_in[14]; const float* b4a = (const float*)d_in[15];
  const float* W4b = (const float*)d_in[16]; const float* b4b = (const float*)d_in[17];
  const float* lin1_w = (const float*)d_in[18]; const float* lin1_b = (const float*)d_in[19];
  const float* gamma  = (const float*)d_in[20]; const float* beta   = (const float*)d_in[21];
  const float* lin2_w = (const float*)d_in[22]; const float* lin2_b = (const float*)d_in[23];
  float* out = (float*)d_out;

  char* ws = (char*)d_ws;
  size_t off = 0;
  auto alloc = [&](size_t bytes) {
    void* p = ws + off; off += (bytes + 255) & ~(size_t)255; return p;
  };
  float* xcat = (float*)alloc((size_t)NP * 512 * 4);   // 32 MB
  float* D    = (float*)alloc((size_t)NP * N_ * 4);    // 64 MB (u/v alias inside)
  int*   idx  = (int*)alloc((size_t)NP * KNN * 4);
  float* sq   = (float*)alloc((size_t)NP * 4);
  unsigned short* wbt1 = (unsigned short*)alloc(64 * 64 * 2);
  unsigned short* wbt2 = (unsigned short*)alloc(64 * 64 * 2);
  unsigned short* wbt3 = (unsigned short*)alloc(128 * 128 * 2);
  unsigned short* wbt4 = (unsigned short*)alloc(256 * 256 * 2);
  float* h      = (float*)alloc(16 * 1024 * 4);
  float* h2     = (float*)alloc(16 * 1024 * 4);
  float* pooled = (float*)alloc(16 * 512 * 4);
  float* part   = (float*)alloc(16 * 8 * 512 * 4);
  unsigned short* u = (unsigned short*)D;              // bf16, aliases D
  unsigned short* v = (unsigned short*)D + (size_t)NP * 256;

  cvtw_kernel<<<dim3(2, 2),   256, 0, stream>>>(W1b, wbt1, 64, 64);
  cvtw_kernel<<<dim3(2, 2),   256, 0, stream>>>(W2b, wbt2, 64, 64);
  cvtw_kernel<<<dim3(4, 4),   256, 0, stream>>>(W3b, wbt3, 128, 128);
  cvtw_kernel<<<dim3(8, 8),   256, 0, stream>>>(W4b, wbt4, 256, 256);

  dim3 pd_grid(16, 16, 16);
  // layer 1: in pos (C=3) -> xcat[:,0:64]
  sqnorm_kernel<<<NP / 256, 256, 0, stream>>>(pos, 3, 0, 3, sq);
  pairdist_kernel<<<pd_grid, 256, 0, stream>>>(pos, 3, 0, 3, sq, D);
  topk_kernel<<<NP / 4, 256, 0, stream>>>(D, idx);
  transform_kernel<<<dim3(NP / 16, 1), 256, 0, stream>>>(pos, 3, 0, 3, 64, W1a, b1a, u, v);
  edge_mlp_kernel<64, 64, 64><<<2048, 320, 0, stream>>>(u, v, idx, wbt1, b1b, xcat, 0);
  // layer 2: in xcat[:,0:64] -> xcat[:,64:128]
  sqnorm_kernel<<<NP / 256, 256, 0, stream>>>(xcat, 512, 0, 64, sq);
  pairdist_kernel<<<pd_grid, 256, 0, stream>>>(xcat, 512, 0, 64, sq, D);
  topk_kernel<<<NP / 4, 256, 0, stream>>>(D, idx);
  transform_kernel<<<dim3(NP / 16, 1), 256, 0, stream>>>(xcat, 512, 0, 64, 64, W2a, b2a, u, v);
  edge_mlp_kernel<64, 64, 64><<<2048, 320, 0, stream>>>(u, v, idx, wbt2, b2b, xcat, 64);
  // layer 3: in xcat[:,64:128] -> xcat[:,128:256]
  sqnorm_kernel<<<NP / 256, 256, 0, stream>>>(xcat, 512, 64, 64, sq);
  pairdist_kernel<<<pd_grid, 256, 0, stream>>>(xcat, 512, 64, 64, sq, D);
  topk_kernel<<<NP / 4, 256, 0, stream>>>(D, idx);
  transform_kernel<<<dim3(NP / 16, 2), 256, 0, stream>>>(xcat, 512, 64, 64, 128, W3a, b3a, u, v);
  edge_mlp_kernel<128, 128, 64><<<2048, 320, 0, stream>>>(u, v, idx, wbt3, b3b, xcat, 128);
  // layer 4: in xcat[:,128:256] -> xcat[:,256:512]
  sqnorm_kernel<<<NP / 256, 256, 0, stream>>>(xcat, 512, 128, 128, sq);
  pairdist_kernel<<<pd_grid, 256, 0, stream>>>(xcat, 512, 128, 128, sq, D);
  topk_kernel<<<NP / 4, 256, 0, stream>>>(D, idx);
  transform_kernel<<<dim3(NP / 16, 4), 256, 0, stream>>>(xcat, 512, 128, 128, 256, W4a, b4a, u, v);
  edge_mlp_kernel<256, 256, 32><<<2048, 320, 0, stream>>>(u, v, idx, wbt4, b4b, xcat, 256);
  // head
  pool1_kernel<<<dim3(16, 8), 256, 0, stream>>>(xcat, part);
  pool2_kernel<<<16, 256, 0, stream>>>(part, pooled);
  lin1_kernel<<<64, 256, 0, stream>>>(pooled, lin1_w, lin1_b, h);
  bn_kernel<<<4, 256, 0, stream>>>(h, gamma, beta, h2);
  lin2_kernel<<<16, 64, 0, stream>>>(h2, lin2_w, lin2_b, out);
}